// Round 1
// 870.450 us; speedup vs baseline: 1.0878x; 1.0878x over previous
//
#include <hip/hip_runtime.h>
#include <hip/hip_bf16.h>
#include <stdint.h>

using bf16 = __hip_bfloat16;
typedef __attribute__((ext_vector_type(8))) short short8;
typedef __attribute__((ext_vector_type(4))) float f32x4;
typedef __attribute__((address_space(3))) unsigned int lds_u32;
typedef const __attribute__((address_space(1))) unsigned int gbl_u32;

#define HSTRIDE 1040
#define NNODES 1025
#define EE 16384
#define MAXDEG 192

__device__ __forceinline__ bf16 f2b(float x) { return __float2bfloat16(x); }
__device__ __forceinline__ float b2f(bf16 x) { return __bfloat162float(x); }
__device__ __forceinline__ float bu2f(unsigned short u) {
    union { unsigned int i; float f; } x;
    x.i = ((unsigned int)u) << 16;
    return x.f;
}

// mask index for logic row: row=(b*512+np)*8+m -> node_mask[(b*1024+512+np)*8+m]
__device__ __forceinline__ size_t midx(int row) {
    int G = row >> 3, m = row & 7, b = G >> 9;
    return (size_t)(G + 512 * (b + 1)) * 8 + m;
}

// ------------------------------------------- transpose f32 -> bf16 [C][R]
__global__ __launch_bounds__(256) void k_transpose_cvt(const float* __restrict__ in,
                                                       bf16* __restrict__ out, int R, int C) {
    __shared__ float tile[32][33];
    int bx = blockIdx.x * 32;
    int by = blockIdx.y * 32;
    int tx = threadIdx.x, ty = threadIdx.y;  // (32,8)
    for (int i = 0; i < 32; i += 8)
        tile[ty + i][tx] = in[(size_t)(by + ty + i) * C + bx + tx];
    __syncthreads();
    for (int i = 0; i < 32; i += 8)
        out[(size_t)(bx + ty + i) * R + by + tx] = f2b(tile[tx][ty + i]);
}

// --------------------- all 6 qkv weight transposes (2 layers x {q,k,v}) in one
__global__ __launch_bounds__(256) void k_transpose_qkv(const float* __restrict__ wq,
                                                       const float* __restrict__ wk,
                                                       const float* __restrict__ wv,
                                                       bf16* __restrict__ out) {
    __shared__ float tile[32][33];
    int z = blockIdx.z;
    int l = z / 3, which = z % 3;
    const float* in = (which == 0 ? wq : which == 1 ? wk : wv) + (size_t)l * 65536;
    bf16* o = out + (size_t)l * 196608 + (size_t)which * 65536;
    int bx = blockIdx.x * 32;
    int by = blockIdx.y * 32;
    int tx = threadIdx.x, ty = threadIdx.y;
    for (int i = 0; i < 32; i += 8)
        tile[ty + i][tx] = in[(size_t)(by + ty + i) * 256 + bx + tx];
    __syncthreads();
    for (int i = 0; i < 32; i += 8)
        o[(size_t)(bx + ty + i) * 256 + by + tx] = f2b(tile[tx][ty + i]);
}

// ---------------- fused small GEMMs: tpe (100 rows) + etewe l0/l1 (50 rows each)
__global__ __launch_bounds__(256) void k_small3(const float* __restrict__ type_table,
                                                const float* __restrict__ type_proj_w,
                                                const float* __restrict__ edge_tt,
                                                const float* __restrict__ gnn_we,
                                                float* __restrict__ tpe,
                                                float* __restrict__ etewe) {
    int r = blockIdx.x, c = threadIdx.x;
    const float* X;
    const float* W;
    float* out;
    if (r < 100) {
        X = type_table + r * 50; W = type_proj_w; out = tpe + r * 256;
    } else if (r < 150) {
        X = edge_tt + (r - 100) * 50; W = gnn_we; out = etewe + (r - 100) * 256;
    } else {
        X = edge_tt + (r - 150) * 50; W = gnn_we + 12800; out = etewe + 12800 + (r - 150) * 256;
    }
    float acc = 0.f;
    for (int k = 0; k < 50; k++) acc += X[k] * W[k * 256 + c];
    out[c] = acc;
}

// ---------------------------------- classifier weight fold (+ beff in block x==0)
__global__ __launch_bounds__(256) void k_weff(const float* __restrict__ cls_w,
                                              const float* __restrict__ cls2_w,
                                              const float* __restrict__ cls_b,
                                              const float* __restrict__ cls2_b,
                                              float* __restrict__ weff,
                                              float* __restrict__ beff) {
    int c = blockIdx.y;
    int wave = threadIdx.x >> 6, lane = threadIdx.x & 63;
    int k = blockIdx.x * 4 + wave;
    float acc = 0.f;
    for (int e = lane; e < 768; e += 64)
        acc += cls_w[(size_t)k * 768 + e] * cls2_w[c * 768 + e];
    for (int s = 32; s > 0; s >>= 1) acc += __shfl_xor(acc, s, 64);
    if (lane == 0) weff[c * 1280 + k] = acc;
    if (blockIdx.x == 0 && wave == 0) {
        float bacc = 0.f;
        for (int e = lane; e < 768; e += 64) bacc += cls_b[e] * cls2_w[c * 768 + e];
        for (int s = 32; s > 0; s >>= 1) bacc += __shfl_xor(bacc, s, 64);
        if (lane == 0) beff[c] = bacc + cls2_b[c];
    }
}

// ------------------------------------------------ text_vec: partials + reduce
__global__ __launch_bounds__(256) void k_textvec_part(const int* __restrict__ sent,
                                                      const float* __restrict__ mask,
                                                      const float* __restrict__ we,
                                                      float* __restrict__ tvp,
                                                      float* __restrict__ msump) {
    int b = blockIdx.x, ch = blockIdx.y, tid = threadIdx.x;
    float a0 = 0.f, a1 = 0.f, a2 = 0.f, ms = 0.f;
    for (int l = ch * 32; l < ch * 32 + 32; l++) {
        int w = sent[b * 256 + l];
        float mm = mask[b * 256 + l];
        const float* row = we + (size_t)w * 768;
        a0 += mm * row[tid];
        a1 += mm * row[tid + 256];
        a2 += mm * row[tid + 512];
        ms += mm;
    }
    float* dst = tvp + (size_t)(b * 8 + ch) * 768;
    dst[tid] = a0;
    dst[tid + 256] = a1;
    dst[tid + 512] = a2;
    if (tid == 0) msump[b * 8 + ch] = ms;
}

__global__ __launch_bounds__(256) void k_tvred(const float* __restrict__ tvp,
                                               const float* __restrict__ msump,
                                               float* __restrict__ tv) {
    int b = blockIdx.x, tid = threadIdx.x;
    float ms = 0.f;
    for (int p = 0; p < 8; p++) ms += msump[b * 8 + p];
    float inv = 1.f / (ms + 1e-9f);
    float a0 = 0.f, a1 = 0.f, a2 = 0.f;
    for (int p = 0; p < 8; p++) {
        const float* s = tvp + (size_t)(b * 8 + p) * 768;
        a0 += s[tid];
        a1 += s[tid + 256];
        a2 += s[tid + 512];
    }
    tv[b * 768 + tid] = a0 * inv;
    tv[b * 768 + tid + 256] = a1 * inv;
    tv[b * 768 + tid + 512] = a2 * inv;
}

// -------------- gemm1 fused: gather-A entity rows, relu+bias, mask-pool out
// XCD-swizzled: 8 n-tiles of one m-tile land on the SAME XCD -> A panel L2-hits
__global__ __launch_bounds__(256) void gemm_mlp1(const int* __restrict__ nodes,
                                                 const float* __restrict__ ent,
                                                 const bf16* __restrict__ Bt,
                                                 const float* __restrict__ b1,
                                                 const float* __restrict__ node_mask,
                                                 bf16* __restrict__ pooledh) {
    __shared__ bf16 As[128][32];
    __shared__ bf16 Bs[128][32];
    const int tid = threadIdx.x;
    // swizzle: xcd = bid&7 (round-robin dispatch), n-tile inner within xcd
    const int bid = blockIdx.x;
    const int j = bid >> 3;
    const int m0 = (((bid & 7) * 32) + (j >> 3)) << 7;  // 256 m-tiles, 32 per xcd
    const int n0 = (j & 7) << 7;                        // 8 n-tiles
    const int lane = tid & 63;
    const int wave = tid >> 6;
    const int wm = (wave >> 1) << 6;
    const int wn = (wave & 1) << 6;
    const int rsel = lane & 15;
    const int qd = lane >> 4;
    const int K = 768;

    const float* arow[4];
    int rl_row = tid >> 3;
    int piece4 = (tid & 7) << 2;
#pragma unroll
    for (int p = 0; p < 4; p++) {
        int grow = m0 + p * 32 + rl_row;
        int id = nodes[midx(grow)];
        arow[p] = ent + (size_t)id * 768 + piece4;
    }

    f32x4 acc[4][4];
#pragma unroll
    for (int i = 0; i < 4; i++)
#pragma unroll
        for (int jj = 0; jj < 4; jj++) acc[i][jj] = (f32x4){0.f, 0.f, 0.f, 0.f};

    const int c0 = tid, r0 = c0 >> 2, kk0 = (c0 & 3) << 3;
    const int c1 = tid + 256, r1 = c1 >> 2, kk1 = (c1 & 3) << 3;

    for (int k0 = 0; k0 < K; k0 += 32) {
        __syncthreads();
        const bf16* gb0 = Bt + (size_t)(n0 + r0) * K + (k0 + kk0);
        __builtin_amdgcn_global_load_lds((gbl_u32*)gb0, (lds_u32*)&Bs[r0][kk0], 16, 0, 0);
        const bf16* gb1 = Bt + (size_t)(n0 + r1) * K + (k0 + kk1);
        __builtin_amdgcn_global_load_lds((gbl_u32*)gb1, (lds_u32*)&Bs[r1][kk1], 16, 0, 0);
#pragma unroll
        for (int p = 0; p < 4; p++) {
            float4 v = *(const float4*)(arow[p] + k0);
            union { bf16 h[4]; uint2 u; } pk;
            pk.h[0] = f2b(v.x); pk.h[1] = f2b(v.y); pk.h[2] = f2b(v.z); pk.h[3] = f2b(v.w);
            *(uint2*)&As[p * 32 + rl_row][piece4] = pk.u;
        }
        __syncthreads();
        short8 af[4], bfr[4];
#pragma unroll
        for (int i = 0; i < 4; i++) af[i] = *(const short8*)&As[wm + i * 16 + rsel][qd << 3];
#pragma unroll
        for (int jj = 0; jj < 4; jj++) bfr[jj] = *(const short8*)&Bs[wn + jj * 16 + rsel][qd << 3];
#pragma unroll
        for (int i = 0; i < 4; i++)
#pragma unroll
            for (int jj = 0; jj < 4; jj++)
                acc[i][jj] = __builtin_amdgcn_mfma_f32_16x16x32_bf16(af[i], bfr[jj], acc[i][jj], 0, 0, 0);
    }
#pragma unroll
    for (int i = 0; i < 4; i++) {
        const int rbase = m0 + wm + i * 16 + (qd << 2);
        float w4[4];
#pragma unroll
        for (int r = 0; r < 4; r++) w4[r] = node_mask[midx(rbase + r)];
        const int Gout = (m0 + wm + i * 16 + ((qd & 2) << 2)) >> 3;
#pragma unroll
        for (int jj = 0; jj < 4; jj++) {
            const int col = n0 + wn + jj * 16 + rsel;
            const float bv = b1[col];
            float s = 0.f;
#pragma unroll
            for (int r = 0; r < 4; r++) s += w4[r] * fmaxf(acc[i][jj][r] + bv, 0.f);
            s += __shfl_xor(s, 16, 64);
            if ((qd & 1) == 0) pooledh[(size_t)Gout * 1024 + col] = f2b(s);
        }
    }
}

// summask[G] = sum_m node_mask over logic group G
__global__ __launch_bounds__(256) void k_summask(const float* __restrict__ node_mask,
                                                 float* __restrict__ summask) {
    int G = blockIdx.x * 256 + threadIdx.x;
    if (G >= 4096) return;
    int b = G >> 9;
    const float* p = node_mask + (size_t)(G + 512 * (b + 1)) * 8;
    float s = 0.f;
    for (int m = 0; m < 8; m++) s += p[m];
    summask[G] = s;
}

// --------------------------------------------------------------- MFMA GEMM
// C = A @ Bt^T.  EPIL: 0=bf16 plain, 4=bias + h-remap f32,
// 5=rowscale*bias -> bf16, remapped to pooled logic rows.
// swz=1: XCD-locality swizzle (requires (M/128)%8==0 and grid%8==0)
template <int EPIL>
__global__ __launch_bounds__(256) void gemm_bt(const bf16* __restrict__ A,
                                               const bf16* __restrict__ Bt,
                                               bf16* __restrict__ Cb, float* __restrict__ Cf,
                                               const float* __restrict__ bias,
                                               const float* __restrict__ smr,
                                               int M, int N, int K, int NT, int swz) {
    __shared__ bf16 As[128][32];
    __shared__ bf16 Bs[128][32];
    const int tid = threadIdx.x;
    const int bid = blockIdx.x;
    int mt, nt;
    if (swz) {
        const int MT8 = (M >> 7) >> 3;
        const int j = bid >> 3;
        mt = (bid & 7) * MT8 + j / NT;
        nt = j - (j / NT) * NT;
    } else {
        mt = bid / NT;
        nt = bid - mt * NT;
    }
    const int m0 = mt << 7;
    const int n0 = nt << 7;
    const int lane = tid & 63;
    const int wave = tid >> 6;
    const int wm = (wave >> 1) << 6;
    const int wn = (wave & 1) << 6;
    const int rsel = lane & 15;
    const int qd = lane >> 4;
    f32x4 acc[4][4];
#pragma unroll
    for (int i = 0; i < 4; i++)
#pragma unroll
        for (int jj = 0; jj < 4; jj++) acc[i][jj] = (f32x4){0.f, 0.f, 0.f, 0.f};

    const int c0 = tid, r0 = c0 >> 2, kk0 = (c0 & 3) << 3;
    const int c1 = tid + 256, r1 = c1 >> 2, kk1 = (c1 & 3) << 3;

    for (int k0 = 0; k0 < K; k0 += 32) {
        __syncthreads();
        {
            const bf16* ga0 = A + (size_t)(m0 + r0) * K + (k0 + kk0);
            __builtin_amdgcn_global_load_lds((gbl_u32*)ga0, (lds_u32*)&As[r0][kk0], 16, 0, 0);
            const bf16* ga1 = A + (size_t)(m0 + r1) * K + (k0 + kk1);
            __builtin_amdgcn_global_load_lds((gbl_u32*)ga1, (lds_u32*)&As[r1][kk1], 16, 0, 0);
            const bf16* gb0 = Bt + (size_t)(n0 + r0) * K + (k0 + kk0);
            __builtin_amdgcn_global_load_lds((gbl_u32*)gb0, (lds_u32*)&Bs[r0][kk0], 16, 0, 0);
            const bf16* gb1 = Bt + (size_t)(n0 + r1) * K + (k0 + kk1);
            __builtin_amdgcn_global_load_lds((gbl_u32*)gb1, (lds_u32*)&Bs[r1][kk1], 16, 0, 0);
        }
        __syncthreads();
        short8 af[4], bfr[4];
#pragma unroll
        for (int i = 0; i < 4; i++) af[i] = *(const short8*)&As[wm + i * 16 + rsel][qd << 3];
#pragma unroll
        for (int jj = 0; jj < 4; jj++) bfr[jj] = *(const short8*)&Bs[wn + jj * 16 + rsel][qd << 3];
#pragma unroll
        for (int i = 0; i < 4; i++)
#pragma unroll
            for (int jj = 0; jj < 4; jj++)
                acc[i][jj] = __builtin_amdgcn_mfma_f32_16x16x32_bf16(af[i], bfr[jj], acc[i][jj], 0, 0, 0);
    }
#pragma unroll
    for (int i = 0; i < 4; i++) {
        const int rbase = m0 + wm + i * 16 + (qd << 2);
        float sm4[4];
        if constexpr (EPIL == 5) {
#pragma unroll
            for (int r = 0; r < 4; r++) sm4[r] = smr[rbase + r];
        }
#pragma unroll
        for (int jj = 0; jj < 4; jj++) {
            const int col = n0 + wn + jj * 16 + rsel;
            float bv = 0.f;
            if constexpr (EPIL == 4 || EPIL == 5) bv = bias[col];
#pragma unroll
            for (int r = 0; r < 4; r++) {
                const int row = rbase + r;
                if constexpr (EPIL == 0) {
                    Cb[(size_t)row * N + col] = f2b(acc[i][jj][r]);
                } else if constexpr (EPIL == 4) {
                    const int bb = row >> 10, nn2 = row & 1023;
                    Cf[((size_t)bb * HSTRIDE + 1 + nn2) * 256 + col] = acc[i][jj][r] + bv;
                } else {  // 5: gemm2 -> pooled logic rows
                    const int dest = row + 512 * ((row >> 9) + 1);
                    Cb[(size_t)dest * N + col] = f2b(acc[i][jj][r] + sm4[r] * bv);
                }
            }
        }
    }
}

// --------------------------------------------------- kg pooling (n < 512)
__global__ __launch_bounds__(256) void k_pool_kg(const int* __restrict__ nodes,
                                                 const float* __restrict__ nmask,
                                                 const float* __restrict__ ent,
                                                 bf16* __restrict__ pooled) {
    int bid = blockIdx.x;  // b*512+n
    int b = bid >> 9, n = bid & 511;
    int tid = threadIdx.x;
    int base = (((b << 10) + n) << 3);
    float a0 = 0.f, a1 = 0.f, a2 = 0.f;
    for (int m = 0; m < 8; m++) {
        float w = nmask[base + m];
        const float* row = ent + (size_t)nodes[base + m] * 768;
        a0 += w * row[tid];
        a1 += w * row[tid + 256];
        a2 += w * row[tid + 512];
    }
    bf16* dst = pooled + (size_t)((b << 10) + n) * 768;
    dst[tid] = f2b(a0);
    dst[tid + 256] = f2b(a1);
    dst[tid + 512] = f2b(a2);
}

// --------------------- type-embed add + h row0 (tv @ proj_w inline) + hbf + pad
__global__ __launch_bounds__(256) void k_tpe_add(const int* __restrict__ ntypes,
                                                 const float* __restrict__ tpe,
                                                 const float* __restrict__ tv,
                                                 const float* __restrict__ proj_w,
                                                 const float* __restrict__ proj_b,
                                                 float* __restrict__ h, bf16* __restrict__ hbf) {
    int i = blockIdx.x;  // 0..1039
    int b = blockIdx.y;
    int c = threadIdx.x;
    size_t idx = ((size_t)b * HSTRIDE + i) * 256 + c;
    if (i < NNODES) {
        int t = ntypes[b * NNODES + i];
        float v;
        if (i == 0) {
            v = proj_b[c];
            for (int k = 0; k < 768; k++) v += tv[b * 768 + k] * proj_w[k * 256 + c];
        } else {
            v = h[idx];
        }
        v += tpe[t * 256 + c];
        h[idx] = v;
        hbf[idx] = f2b(v);
    } else {
        h[idx] = 0.f;
        hbf[idx] = f2b(0.f);
    }
}

// ----------------------------------------------------------------- CSR build
__global__ void k_zero(int* p, int n) {
    int i = blockIdx.x * 256 + threadIdx.x;
    if (i < n) p[i] = 0;
}

__global__ __launch_bounds__(256) void k_count(const int* __restrict__ edges,
                                               int* __restrict__ counts) {
    int flat = blockIdx.x * 256 + threadIdx.x;
    int b = flat >> 14, e = flat & (EE - 1);
    int d = edges[b * 2 * EE + EE + e];
    atomicAdd(&counts[b * NNODES + d], 1);
}

__global__ __launch_bounds__(256) void k_scan(const int* __restrict__ counts,
                                              int* __restrict__ offs, int* __restrict__ cursor) {
    int b = blockIdx.x, t = threadIdx.x;
    __shared__ int tsum[256];
    int beg = t * 5;
    int end = beg + 5;
    if (end > NNODES) end = NNODES;
    int cl[5];
    int s = 0;
    for (int i = beg; i < end; i++) {
        int v = counts[b * NNODES + i];
        cl[i - beg] = v;
        s += v;
    }
    tsum[t] = s;
    __syncthreads();
    for (int d = 1; d < 256; d <<= 1) {
        int v = tsum[t];
        int vo = (t >= d) ? tsum[t - d] : 0;
        __syncthreads();
        tsum[t] = v + vo;
        __syncthreads();
    }
    int run = (t == 0) ? 0 : tsum[t - 1];
    for (int i = beg; i < end; i++) {
        offs[b * 1026 + i] = run;
        cursor[b * NNODES + i] = run;
        run += cl[i - beg];
    }
    if (beg == NNODES) offs[b * 1026 + NNODES] = run;
}

__global__ __launch_bounds__(256) void k_scatter(const int* __restrict__ edges,
                                                 int* __restrict__ cursor, int* __restrict__ eord) {
    int flat = blockIdx.x * 256 + threadIdx.x;
    int b = flat >> 14, e = flat & (EE - 1);
    int d = edges[b * 2 * EE + EE + e];
    int pos = atomicAdd(&cursor[b * NNODES + d], 1);
    eord[b * EE + pos] = e;
}

// ------------------------------------------------ GNN attention per dst node
// qkv now bf16; aggregation wave-parallelized (4 waves x 4 cols/lane)
__global__ __launch_bounds__(256) void k_gnn_node(const int* __restrict__ edges,
                                                  const int* __restrict__ etypes,
                                                  const int* __restrict__ offs,
                                                  const int* __restrict__ eord,
                                                  const float* __restrict__ etewe,
                                                  const bf16* __restrict__ qkv,
                                                  float* __restrict__ h, bf16* __restrict__ hbf) {
    int bid = blockIdx.x;
    int b = bid / NNODES, n = bid % NNODES;
    int o0 = offs[b * 1026 + n];
    int deg = offs[b * 1026 + n + 1] - o0;
    if (deg > MAXDEG) deg = MAXDEG;
    int tid = threadIdx.x, lane = tid & 63, wave = tid >> 6;
    __shared__ float qs[256];
    __shared__ float elog[MAXDEG][4];
    __shared__ int srcs[MAXDEG];
    __shared__ float smax[4], sden[4];
    __shared__ float vpart[4][256];
    size_t qbase = ((size_t)(b * HSTRIDE + n)) * 768;
    qs[tid] = b2f(qkv[qbase + tid]);
    __syncthreads();
    for (int i = wave; i < deg; i += 4) {
        int e = eord[b * EE + o0 + i];
        int src = edges[b * 2 * EE + e];
        int et = etypes[b * EE + e];
        const bf16* krow = qkv + ((size_t)(b * HSTRIDE + src)) * 768 + 256;
        const float* kerow = etewe + et * 256;
        float sum[4];
#pragma unroll
        for (int hh = 0; hh < 4; hh++) {
            float v = qs[hh * 64 + lane] * (b2f(krow[hh * 64 + lane]) + kerow[hh * 64 + lane]);
            for (int s = 32; s > 0; s >>= 1) v += __shfl_xor(v, s, 64);
            sum[hh] = v;
        }
        if (lane == 0) {
            srcs[i] = src;
#pragma unroll
            for (int hh = 0; hh < 4; hh++) elog[i][hh] = sum[hh] * 0.125f;
        }
    }
    __syncthreads();
    if (deg > 0) {  // 4 waves, one head each: lane-parallel max + denom
        int hh = wave;
        float m = -1e30f;
        for (int i = lane; i < deg; i += 64) m = fmaxf(m, elog[i][hh]);
        for (int s = 32; s > 0; s >>= 1) m = fmaxf(m, __shfl_xor(m, s, 64));
        float den = 0.f;
        for (int i = lane; i < deg; i += 64) den += expf(elog[i][hh] - m);
        for (int s = 32; s > 0; s >>= 1) den += __shfl_xor(den, s, 64);
        if (lane == 0) { smax[hh] = m; sden[hh] = den; }
    }
    __syncthreads();
    for (int i = tid; i < deg; i += 256) {
#pragma unroll
        for (int hh = 0; hh < 4; hh++)
            elog[i][hh] = expf(elog[i][hh] - smax[hh]) / (sden[hh] + 1e-9f);
    }
    __syncthreads();
    // aggregation: wave w takes edges w::4, lane covers cols lane*4..lane*4+3
    float a0 = 0.f, a1 = 0.f, a2 = 0.f, a3 = 0.f;
    const int hsel = lane >> 4;  // head of these 4 cols
    for (int i = wave; i < deg; i += 4) {
        float w = elog[i][hsel];
        const bf16* vrow = qkv + ((size_t)(b * HSTRIDE + srcs[i])) * 768 + 512 + lane * 4;
        ushort4 u = *reinterpret_cast<const ushort4*>(vrow);
        a0 += w * bu2f(u.x);
        a1 += w * bu2f(u.y);
        a2 += w * bu2f(u.z);
        a3 += w * bu2f(u.w);
    }
    vpart[wave][lane * 4 + 0] = a0;
    vpart[wave][lane * 4 + 1] = a1;
    vpart[wave][lane * 4 + 2] = a2;
    vpart[wave][lane * 4 + 3] = a3;
    __syncthreads();
    float acc = vpart[0][tid] + vpart[1][tid] + vpart[2][tid] + vpart[3][tid];
    size_t hidx = ((size_t)(b * HSTRIDE + n)) * 256 + tid;
    float v = fmaxf(h[hidx] + acc, 0.f);
    h[hidx] = v;
    hbf[hidx] = f2b(v);
}

// ----------------------------------------------------------------- classifier
__global__ __launch_bounds__(256) void k_cls(const float* __restrict__ h,
                                             const float* __restrict__ tv,
                                             const float* __restrict__ weff,
                                             const float* __restrict__ beff,
                                             float* __restrict__ out) {
    int bc = blockIdx.x;
    int b = bc / 50, c = bc % 50;
    int tid = threadIdx.x;
    const float* we = weff + c * 1280;
    float acc = 0.f;
    for (int kk = tid; kk < 1280; kk += 256) {
        float f;
        if (kk < 256) f = h[((size_t)(b * HSTRIDE)) * 256 + kk];
        else if (kk < 512) f = h[((size_t)(b * HSTRIDE + 1 + c)) * 256 + (kk - 256)];
        else f = tv[b * 768 + (kk - 512)];
        acc += f * we[kk];
    }
    __shared__ float red[256];
    red[tid] = acc;
    __syncthreads();
    for (int s = 128; s > 0; s >>= 1) {
        if (tid < s) red[tid] += red[tid + s];
        __syncthreads();
    }
    if (tid == 0) out[b * 50 + c] = red[0] + beff[c];
}

// ======================================================================
extern "C" void kernel_launch(void* const* d_in, const int* in_sizes, int n_in,
                              void* d_out, int out_size, void* d_ws, size_t ws_size,
                              hipStream_t stream) {
    (void)in_sizes; (void)n_in; (void)out_size; (void)ws_size;
    const int* sentence       = (const int*)d_in[0];
    const float* mask         = (const float*)d_in[1];
    const int* nodes          = (const int*)d_in[2];
    const float* node_mask    = (const float*)d_in[3];
    const int* node_types     = (const int*)d_in[4];
    const int* edges          = (const int*)d_in[5];
    const int* edge_types     = (const int*)d_in[6];
    const float* word_embed   = (const float*)d_in[7];
    const float* entity_table = (const float*)d_in[8];
    const float* type_table   = (const float*)d_in[9];
    const float* mlp_w1       = (const float*)d_in[10];
    const float* mlp_b1       = (const float*)d_in[11];
    const float* mlp_w2       = (const float*)d_in[12];
    const float* mlp_b2       = (const float*)d_in[13];
    const float* ntw_w        = (const float*)d_in[14];
    const float* proj_w       = (const float*)d_in[15];
    const float* proj_b       = (const float*)d_in[16];
    const float* type_proj_w  = (const float*)d_in[17];
    const float* edge_tt      = (const float*)d_in[18];
    const float* gnn_wq       = (const float*)d_in[19];
    const float* gnn_wk       = (const float*)d_in[20];
    const float* gnn_wv       = (const float*)d_in[21];
    const float* gnn_we       = (const float*)d_in[22];
    const float* cls_w        = (const float*)d_in[23];
    const float* cls_b        = (const float*)d_in[24];
    const float* cls2_w       = (const float*)d_in[25];
    const float* cls2_b       = (const float*)d_in[26];

    char* ws = (char*)d_ws;
    size_t off = 0;
    auto alloc = [&](size_t bytes) {
        size_t r = off;
        off += (bytes + 255) & ~((size_t)255);
        return r;
    };
    bf16* w1t     = (bf16*)(ws + alloc((size_t)1024 * 768 * 2));
    bf16* w2t     = (bf16*)(ws + alloc((size_t)768 * 1024 * 2));
    bf16* ntwt    = (bf16*)(ws + alloc((size_t)768 * 768 * 2));
    bf16* projt   = (bf16*)(ws + alloc((size_t)256 * 768 * 2));
    bf16* wqkvt   = (bf16*)(ws + alloc((size_t)2 * 768 * 256 * 2));
    float* tpe    = (float*)(ws + alloc((size_t)100 * 256 * 4));
    float* etewe  = (float*)(ws + alloc((size_t)2 * 50 * 256 * 4));
    float* weff   = (float*)(ws + alloc((size_t)50 * 1280 * 4));
    float* beff   = (float*)(ws + alloc(256));
    float* tv     = (float*)(ws + alloc((size_t)8 * 768 * 4));
    float* tvp    = (float*)(ws + alloc((size_t)64 * 768 * 4));
    float* msump  = (float*)(ws + alloc((size_t)64 * 4));
    float* summask= (float*)(ws + alloc((size_t)4096 * 4));
    int* counts   = (int*)(ws + alloc((size_t)8 * NNODES * 4));
    int* offs     = (int*)(ws + alloc((size_t)8 * 1026 * 4));
    int* cursor   = (int*)(ws + alloc((size_t)8 * NNODES * 4));
    int* eord     = (int*)(ws + alloc((size_t)8 * EE * 4));
    bf16* pooledh = (bf16*)(ws + alloc((size_t)4096 * 1024 * 2));
    bf16* pooled  = (bf16*)(ws + alloc((size_t)8192 * 768 * 2));
    bf16* ne2     = (bf16*)(ws + alloc((size_t)8192 * 768 * 2));
    float* h      = (float*)(ws + alloc((size_t)8 * HSTRIDE * 256 * 4));
    bf16* hbf     = (bf16*)(ws + alloc((size_t)8 * HSTRIDE * 256 * 2));
    bf16* qkv     = (bf16*)(ws + alloc((size_t)8 * HSTRIDE * 768 * 2));

    dim3 tb(32, 8);
    // weight transposes (f32 -> bf16)
    k_transpose_cvt<<<dim3(32, 24), tb, 0, stream>>>(mlp_w1, w1t, 768, 1024);
    k_transpose_cvt<<<dim3(24, 32), tb, 0, stream>>>(mlp_w2, w2t, 1024, 768);
    k_transpose_cvt<<<dim3(24, 24), tb, 0, stream>>>(ntw_w, ntwt, 768, 768);
    k_transpose_cvt<<<dim3(8, 24), tb, 0, stream>>>(proj_w, projt, 768, 256);
    k_transpose_qkv<<<dim3(8, 8, 6), tb, 0, stream>>>(gnn_wq, gnn_wk, gnn_wv, wqkvt);
    // small precomputes
    k_small3<<<200, 256, 0, stream>>>(type_table, type_proj_w, edge_tt, gnn_we, tpe, etewe);
    k_weff<<<dim3(320, 50), 256, 0, stream>>>(cls_w, cls2_w, cls_b, cls2_b, weff, beff);
    k_textvec_part<<<dim3(8, 8), 256, 0, stream>>>(sentence, mask, word_embed, tvp, msump);
    k_tvred<<<8, 256, 0, stream>>>(tvp, msump, tv);

    // MLP over logic nodes: fused gather + GEMM1 + relu + mask-pool (XCD-swizzled)
    gemm_mlp1<<<2048, 256, 0, stream>>>(nodes, entity_table, w1t, mlp_b1, node_mask, pooledh);
    k_summask<<<16, 256, 0, stream>>>(node_mask, summask);
    // GEMM2 on pooled hidden (M=4096), epilogue scatters into pooled logic rows
    gemm_bt<5><<<192, 256, 0, stream>>>(pooledh, w2t, pooled, nullptr, mlp_b2, summask, 4096, 768, 1024, 6, 1);
    // kg pooling
    k_pool_kg<<<4096, 256, 0, stream>>>(nodes, node_mask, entity_table, pooled);
    // ntw + proj
    gemm_bt<0><<<384, 256, 0, stream>>>(pooled, ntwt, ne2, nullptr, nullptr, nullptr, 8192, 768, 768, 6, 1);
    gemm_bt<4><<<128, 256, 0, stream>>>(ne2, projt, nullptr, h, proj_b, nullptr, 8192, 256, 768, 2, 1);
    k_tpe_add<<<dim3(1040, 8), 256, 0, stream>>>(node_types, tpe, tv, proj_w, proj_b, h, hbf);

    // CSR by dst (shared by both layers)
    k_zero<<<(8 * NNODES + 255) / 256, 256, 0, stream>>>(counts, 8 * NNODES);
    k_count<<<512, 256, 0, stream>>>(edges, counts);
    k_scan<<<8, 256, 0, stream>>>(counts, offs, cursor);
    k_scatter<<<512, 256, 0, stream>>>(edges, cursor, eord);

    for (int l = 0; l < 2; l++) {
        // qkv in bf16 (EPIL=0); M/128=65 not %8 -> no swizzle
        gemm_bt<0><<<390, 256, 0, stream>>>(hbf, wqkvt + l * 196608, qkv, nullptr, nullptr, nullptr, 8320, 768, 256, 6, 0);
        k_gnn_node<<<8 * NNODES, 256, 0, stream>>>(edges, edge_types, offs, eord,
                                                   etewe + l * 12800, qkv, h, hbf);
    }
    k_cls<<<400, 256, 0, stream>>>(h, tv, weff, beff, (float*)d_out);
}

// Round 2
// 804.470 us; speedup vs baseline: 1.1770x; 1.0820x over previous
//
#include <hip/hip_runtime.h>
#include <hip/hip_bf16.h>
#include <stdint.h>

using bf16 = __hip_bfloat16;
typedef __attribute__((ext_vector_type(8))) short short8;
typedef __attribute__((ext_vector_type(4))) float f32x4;
typedef __attribute__((address_space(3))) unsigned int lds_u32;
typedef const __attribute__((address_space(1))) unsigned int gbl_u32;

#define HSTRIDE 1040
#define NNODES 1025
#define EE 16384
#define MAXDEG 192

__device__ __forceinline__ bf16 f2b(float x) { return __float2bfloat16(x); }
__device__ __forceinline__ float b2f(bf16 x) { return __bfloat162float(x); }
__device__ __forceinline__ float bu2f(unsigned short u) {
    union { unsigned int i; float f; } x;
    x.i = ((unsigned int)u) << 16;
    return x.f;
}

// mask index for logic row: row=(b*512+np)*8+m -> node_mask[(b*1024+512+np)*8+m]
__device__ __forceinline__ size_t midx(int row) {
    int G = row >> 3, m = row & 7, b = G >> 9;
    return (size_t)(G + 512 * (b + 1)) * 8 + m;
}

// ---------------------------------------------------------- shared GEMM body
// C = A @ Bt^T.  EPIL: 0=bf16 plain, 4=bias + h-remap f32,
// 5=rowscale*bias -> bf16, remapped to pooled logic rows.
// swz=1: XCD-locality swizzle (requires (M/128)%8==0 and range grid %8==0,
// range must start at blockIdx 0 so round-robin XCD mapping holds)
template <int EPIL>
__device__ __forceinline__ void gemm_body(const bf16* __restrict__ A, const bf16* __restrict__ Bt,
                                          bf16* __restrict__ Cb, float* __restrict__ Cf,
                                          const float* __restrict__ bias,
                                          const float* __restrict__ smr,
                                          int M, int N, int K, int NT, int swz, int bid) {
    __shared__ bf16 As[128][32];
    __shared__ bf16 Bs[128][32];
    const int tid = threadIdx.x;
    int mt, nt;
    if (swz) {
        const int MT8 = (M >> 7) >> 3;
        const int j = bid >> 3;
        mt = (bid & 7) * MT8 + j / NT;
        nt = j - (j / NT) * NT;
    } else {
        mt = bid / NT;
        nt = bid - mt * NT;
    }
    const int m0 = mt << 7;
    const int n0 = nt << 7;
    const int lane = tid & 63;
    const int wave = tid >> 6;
    const int wm = (wave >> 1) << 6;
    const int wn = (wave & 1) << 6;
    const int rsel = lane & 15;
    const int qd = lane >> 4;
    f32x4 acc[4][4];
#pragma unroll
    for (int i = 0; i < 4; i++)
#pragma unroll
        for (int jj = 0; jj < 4; jj++) acc[i][jj] = (f32x4){0.f, 0.f, 0.f, 0.f};

    const int c0 = tid, r0 = c0 >> 2, kk0 = (c0 & 3) << 3;
    const int c1 = tid + 256, r1 = c1 >> 2, kk1 = (c1 & 3) << 3;

    for (int k0 = 0; k0 < K; k0 += 32) {
        __syncthreads();
        {
            const bf16* ga0 = A + (size_t)(m0 + r0) * K + (k0 + kk0);
            __builtin_amdgcn_global_load_lds((gbl_u32*)ga0, (lds_u32*)&As[r0][kk0], 16, 0, 0);
            const bf16* ga1 = A + (size_t)(m0 + r1) * K + (k0 + kk1);
            __builtin_amdgcn_global_load_lds((gbl_u32*)ga1, (lds_u32*)&As[r1][kk1], 16, 0, 0);
            const bf16* gb0 = Bt + (size_t)(n0 + r0) * K + (k0 + kk0);
            __builtin_amdgcn_global_load_lds((gbl_u32*)gb0, (lds_u32*)&Bs[r0][kk0], 16, 0, 0);
            const bf16* gb1 = Bt + (size_t)(n0 + r1) * K + (k0 + kk1);
            __builtin_amdgcn_global_load_lds((gbl_u32*)gb1, (lds_u32*)&Bs[r1][kk1], 16, 0, 0);
        }
        __syncthreads();
        short8 af[4], bfr[4];
#pragma unroll
        for (int i = 0; i < 4; i++) af[i] = *(const short8*)&As[wm + i * 16 + rsel][qd << 3];
#pragma unroll
        for (int jj = 0; jj < 4; jj++) bfr[jj] = *(const short8*)&Bs[wn + jj * 16 + rsel][qd << 3];
#pragma unroll
        for (int i = 0; i < 4; i++)
#pragma unroll
            for (int jj = 0; jj < 4; jj++)
                acc[i][jj] = __builtin_amdgcn_mfma_f32_16x16x32_bf16(af[i], bfr[jj], acc[i][jj], 0, 0, 0);
    }
#pragma unroll
    for (int i = 0; i < 4; i++) {
        const int rbase = m0 + wm + i * 16 + (qd << 2);
        float sm4[4];
        if constexpr (EPIL == 5) {
#pragma unroll
            for (int r = 0; r < 4; r++) sm4[r] = smr[rbase + r];
        }
#pragma unroll
        for (int jj = 0; jj < 4; jj++) {
            const int col = n0 + wn + jj * 16 + rsel;
            float bv = 0.f;
            if constexpr (EPIL == 4 || EPIL == 5) bv = bias[col];
#pragma unroll
            for (int r = 0; r < 4; r++) {
                const int row = rbase + r;
                if constexpr (EPIL == 0) {
                    Cb[(size_t)row * N + col] = f2b(acc[i][jj][r]);
                } else if constexpr (EPIL == 4) {
                    const int bb = row >> 10, nn2 = row & 1023;
                    Cf[((size_t)bb * HSTRIDE + 1 + nn2) * 256 + col] = acc[i][jj][r] + bv;
                } else {  // 5
                    const int dest = row + 512 * ((row >> 9) + 1);
                    Cb[(size_t)dest * N + col] = f2b(acc[i][jj][r] + sm4[r] * bv);
                }
            }
        }
    }
}

template <int EPIL>
__global__ __launch_bounds__(256) void gemm_bt(const bf16* __restrict__ A,
                                               const bf16* __restrict__ Bt,
                                               bf16* __restrict__ Cb, float* __restrict__ Cf,
                                               const float* __restrict__ bias,
                                               const float* __restrict__ smr,
                                               int M, int N, int K, int NT, int swz) {
    gemm_body<EPIL>(A, Bt, Cb, Cf, bias, smr, M, N, K, NT, swz, blockIdx.x);
}

// ------------------------------------------------- transpose helper (32x32)
__device__ __forceinline__ void tr_tile(const float* __restrict__ in, bf16* __restrict__ out,
                                        int R, int C, int gx, int gy, int tid,
                                        float (*tile)[33]) {
    int tx = tid & 31, ty = tid >> 5;  // 32 x 8
    int bx = gx * 32, by = gy * 32;
    for (int i = 0; i < 32; i += 8)
        tile[ty + i][tx] = in[(size_t)(by + ty + i) * C + bx + tx];
    __syncthreads();
    for (int i = 0; i < 32; i += 8)
        out[(size_t)(bx + ty + i) * R + by + tx] = f2b(tile[tx][ty + i]);
}

// ================= L1: all independent preprocessing in ONE kernel ==========
__global__ __launch_bounds__(256) void k_prep(
    const float* __restrict__ mlp_w1, const float* __restrict__ mlp_w2,
    const float* __restrict__ ntw_w, const float* __restrict__ proj_w,
    const float* __restrict__ gnn_wq, const float* __restrict__ gnn_wk,
    const float* __restrict__ gnn_wv,
    const float* __restrict__ type_table, const float* __restrict__ type_proj_w,
    const float* __restrict__ edge_tt, const float* __restrict__ gnn_we,
    const float* __restrict__ cls_w, const float* __restrict__ cls2_w,
    const float* __restrict__ cls_b, const float* __restrict__ cls2_b,
    const int* __restrict__ sent, const float* __restrict__ maskp,
    const float* __restrict__ we,
    bf16* __restrict__ w1t, bf16* __restrict__ w2t, bf16* __restrict__ ntwbf,
    bf16* __restrict__ projt, bf16* __restrict__ wqkvt,
    float* __restrict__ tpe, float* __restrict__ etewe,
    float* __restrict__ weff, float* __restrict__ beff,
    float* __restrict__ tvp, float* __restrict__ msump, int* __restrict__ counts) {
    __shared__ float tile[32][33];
    int u = blockIdx.x;
    int tid = threadIdx.x;
    if (u < 768) {  // mlp_w1 [768,1024] -> w1t [1024][768]
        tr_tile(mlp_w1, w1t, 768, 1024, u % 32, u / 32, tid, tile);
        return;
    }
    u -= 768;
    if (u < 768) {  // mlp_w2 [1024,768] -> w2t [768][1024]
        tr_tile(mlp_w2, w2t, 1024, 768, u % 24, u / 24, tid, tile);
        return;
    }
    u -= 768;
    if (u < 576) {  // ntw_w straight f32->bf16 copy (no transpose)
        int base = (u * 256 + tid) * 4;
        float4 v = *(const float4*)(ntw_w + base);
        union { bf16 h[4]; uint2 q; } pk;
        pk.h[0] = f2b(v.x); pk.h[1] = f2b(v.y); pk.h[2] = f2b(v.z); pk.h[3] = f2b(v.w);
        *(uint2*)(ntwbf + base) = pk.q;
        return;
    }
    u -= 576;
    if (u < 192) {  // proj_w [768,256] -> projt [256][768]
        tr_tile(proj_w, projt, 768, 256, u % 8, u / 8, tid, tile);
        return;
    }
    u -= 192;
    if (u < 384) {  // qkv weights: 6 x [256,256] transpose
        int z = u / 64, v = u % 64;
        int l = z / 3, which = z % 3;
        const float* in = (which == 0 ? gnn_wq : which == 1 ? gnn_wk : gnn_wv) + (size_t)l * 65536;
        bf16* o = wqkvt + (size_t)l * 196608 + (size_t)which * 65536;
        tr_tile(in, o, 256, 256, v % 8, v / 8, tid, tile);
        return;
    }
    u -= 384;
    if (u < 200) {  // small GEMMs: tpe(100) + etewe l0(50)/l1(50)
        const float* X;
        const float* W;
        float* out;
        if (u < 100) {
            X = type_table + u * 50; W = type_proj_w; out = tpe + u * 256;
        } else if (u < 150) {
            X = edge_tt + (u - 100) * 50; W = gnn_we; out = etewe + (u - 100) * 256;
        } else {
            X = edge_tt + (u - 150) * 50; W = gnn_we + 12800; out = etewe + 12800 + (u - 150) * 256;
        }
        float acc = 0.f;
        for (int k = 0; k < 50; k++) acc += X[k] * W[k * 256 + tid];
        out[tid] = acc;
        return;
    }
    u -= 200;
    if (u < 320) {  // weff: wave holds cls_w row in regs, loops 50 classes
        int wave = tid >> 6, lane = tid & 63;
        int k = u * 4 + wave;
        float wrow[12];
#pragma unroll
        for (int t = 0; t < 12; t++) wrow[t] = cls_w[(size_t)k * 768 + t * 64 + lane];
        for (int c = 0; c < 50; c++) {
            const float* c2 = cls2_w + c * 768;
            float acc = 0.f;
#pragma unroll
            for (int t = 0; t < 12; t++) acc += wrow[t] * c2[t * 64 + lane];
            for (int s = 32; s > 0; s >>= 1) acc += __shfl_xor(acc, s, 64);
            if (lane == 0) weff[c * 1280 + k] = acc;
        }
        if (u == 0) {  // beff folded: 4 waves cover 50 classes
            float brow[12];
#pragma unroll
            for (int t = 0; t < 12; t++) brow[t] = cls_b[t * 64 + lane];
            for (int c = wave; c < 50; c += 4) {
                const float* c2 = cls2_w + c * 768;
                float acc = 0.f;
#pragma unroll
                for (int t = 0; t < 12; t++) acc += brow[t] * c2[t * 64 + lane];
                for (int s = 32; s > 0; s >>= 1) acc += __shfl_xor(acc, s, 64);
                if (lane == 0) beff[c] = acc + cls2_b[c];
            }
        }
        return;
    }
    u -= 320;
    if (u < 64) {  // textvec partials: b = u>>3, ch = u&7
        int b = u >> 3, ch = u & 7;
        float a0 = 0.f, a1 = 0.f, a2 = 0.f, ms = 0.f;
        for (int l = ch * 32; l < ch * 32 + 32; l++) {
            int w = sent[b * 256 + l];
            float mm = maskp[b * 256 + l];
            const float* row = we + (size_t)w * 768;
            a0 += mm * row[tid];
            a1 += mm * row[tid + 256];
            a2 += mm * row[tid + 512];
            ms += mm;
        }
        float* dst = tvp + (size_t)(b * 8 + ch) * 768;
        dst[tid] = a0;
        dst[tid + 256] = a1;
        dst[tid + 512] = a2;
        if (tid == 0) msump[b * 8 + ch] = ms;
        return;
    }
    u -= 64;
    {  // zero CSR counts (33 blocks)
        int i = u * 256 + tid;
        if (i < 8 * NNODES) counts[i] = 0;
    }
}

// ===== L2: fold-GEMM (W_np^T = projt @ ntwbf^T) + tvred + summask + count ===
__global__ __launch_bounds__(256) void k_mid(
    const bf16* __restrict__ projt, const bf16* __restrict__ ntwbf, bf16* __restrict__ wnpt,
    const float* __restrict__ tvp, const float* __restrict__ msump, float* __restrict__ tv,
    const float* __restrict__ node_mask, float* __restrict__ summask,
    const int* __restrict__ edges, int* __restrict__ counts) {
    int u = blockIdx.x;
    int tid = threadIdx.x;
    if (u < 12) {
        // wnpt[n][j] = sum_m projt[n][m]*ntwbf[j][m] = (ntw_w @ proj_w)^T
        gemm_body<0>(projt, ntwbf, wnpt, nullptr, nullptr, nullptr, 256, 768, 768, 6, 0, u);
        return;
    }
    u -= 12;
    if (u < 8) {  // tvred
        int b = u;
        float ms = 0.f;
        for (int p = 0; p < 8; p++) ms += msump[b * 8 + p];
        float inv = 1.f / (ms + 1e-9f);
        float a0 = 0.f, a1 = 0.f, a2 = 0.f;
        for (int p = 0; p < 8; p++) {
            const float* s = tvp + (size_t)(b * 8 + p) * 768;
            a0 += s[tid];
            a1 += s[tid + 256];
            a2 += s[tid + 512];
        }
        tv[b * 768 + tid] = a0 * inv;
        tv[b * 768 + tid + 256] = a1 * inv;
        tv[b * 768 + tid + 512] = a2 * inv;
        return;
    }
    u -= 8;
    if (u < 16) {  // summask
        int G = u * 256 + tid;
        if (G < 4096) {
            int b = G >> 9;
            const float* p = node_mask + (size_t)(G + 512 * (b + 1)) * 8;
            float s = 0.f;
            for (int m = 0; m < 8; m++) s += p[m];
            summask[G] = s;
        }
        return;
    }
    u -= 16;
    {  // CSR count (512 blocks)
        int flat = u * 256 + tid;
        int b = flat >> 14, e = flat & (EE - 1);
        int d = edges[b * 2 * EE + EE + e];
        atomicAdd(&counts[b * NNODES + d], 1);
    }
}

// ===== L3: gemm_mlp1 (2048, XCD-swizzled) + CSR scan (8) =====================
__global__ __launch_bounds__(256) void k_mlp1_scan(
    const int* __restrict__ nodes, const float* __restrict__ ent,
    const bf16* __restrict__ Bt, const float* __restrict__ b1,
    const float* __restrict__ node_mask, bf16* __restrict__ pooledh,
    const int* __restrict__ counts, int* __restrict__ offs, int* __restrict__ cursor) {
    __shared__ bf16 As[128][32];
    __shared__ bf16 Bs[128][32];
    __shared__ int tsum[256];
    const int tid = threadIdx.x;
    const int bid = blockIdx.x;
    if (bid >= 2048) {  // ---- scan ----
        int b = bid - 2048, t = tid;
        int beg = t * 5;
        int end = beg + 5;
        if (end > NNODES) end = NNODES;
        int cl[5];
        int s = 0;
        for (int i = beg; i < end; i++) {
            int v = counts[b * NNODES + i];
            cl[i - beg] = v;
            s += v;
        }
        tsum[t] = s;
        __syncthreads();
        for (int d = 1; d < 256; d <<= 1) {
            int v = tsum[t];
            int vo = (t >= d) ? tsum[t - d] : 0;
            __syncthreads();
            tsum[t] = v + vo;
            __syncthreads();
        }
        int run = (t == 0) ? 0 : tsum[t - 1];
        for (int i = beg; i < end; i++) {
            offs[b * 1026 + i] = run;
            cursor[b * NNODES + i] = run;
            run += cl[i - beg];
        }
        if (beg == NNODES) offs[b * 1026 + NNODES] = run;
        return;
    }
    // ---- gemm_mlp1: gather-A + GEMM + relu + mask-pool, XCD-swizzled ----
    const int j = bid >> 3;
    const int m0 = (((bid & 7) * 32) + (j >> 3)) << 7;
    const int n0 = (j & 7) << 7;
    const int lane = tid & 63;
    const int wave = tid >> 6;
    const int wm = (wave >> 1) << 6;
    const int wn = (wave & 1) << 6;
    const int rsel = lane & 15;
    const int qd = lane >> 4;
    const int K = 768;

    const float* arow[4];
    int rl_row = tid >> 3;
    int piece4 = (tid & 7) << 2;
#pragma unroll
    for (int p = 0; p < 4; p++) {
        int grow = m0 + p * 32 + rl_row;
        int id = nodes[midx(grow)];
        arow[p] = ent + (size_t)id * 768 + piece4;
    }

    f32x4 acc[4][4];
#pragma unroll
    for (int i = 0; i < 4; i++)
#pragma unroll
        for (int jj = 0; jj < 4; jj++) acc[i][jj] = (f32x4){0.f, 0.f, 0.f, 0.f};

    const int c0 = tid, r0 = c0 >> 2, kk0 = (c0 & 3) << 3;
    const int c1 = tid + 256, r1 = c1 >> 2, kk1 = (c1 & 3) << 3;

    for (int k0 = 0; k0 < K; k0 += 32) {
        __syncthreads();
        const bf16* gb0 = Bt + (size_t)(n0 + r0) * K + (k0 + kk0);
        __builtin_amdgcn_global_load_lds((gbl_u32*)gb0, (lds_u32*)&Bs[r0][kk0], 16, 0, 0);
        const bf16* gb1 = Bt + (size_t)(n0 + r1) * K + (k0 + kk1);
        __builtin_amdgcn_global_load_lds((gbl_u32*)gb1, (lds_u32*)&Bs[r1][kk1], 16, 0, 0);
#pragma unroll
        for (int p = 0; p < 4; p++) {
            float4 v = *(const float4*)(arow[p] + k0);
            union { bf16 h[4]; uint2 u; } pk;
            pk.h[0] = f2b(v.x); pk.h[1] = f2b(v.y); pk.h[2] = f2b(v.z); pk.h[3] = f2b(v.w);
            *(uint2*)&As[p * 32 + rl_row][piece4] = pk.u;
        }
        __syncthreads();
        short8 af[4], bfr[4];
#pragma unroll
        for (int i = 0; i < 4; i++) af[i] = *(const short8*)&As[wm + i * 16 + rsel][qd << 3];
#pragma unroll
        for (int jj = 0; jj < 4; jj++) bfr[jj] = *(const short8*)&Bs[wn + jj * 16 + rsel][qd << 3];
#pragma unroll
        for (int i = 0; i < 4; i++)
#pragma unroll
            for (int jj = 0; jj < 4; jj++)
                acc[i][jj] = __builtin_amdgcn_mfma_f32_16x16x32_bf16(af[i], bfr[jj], acc[i][jj], 0, 0, 0);
    }
#pragma unroll
    for (int i = 0; i < 4; i++) {
        const int rbase = m0 + wm + i * 16 + (qd << 2);
        float w4[4];
#pragma unroll
        for (int r = 0; r < 4; r++) w4[r] = node_mask[midx(rbase + r)];
        const int Gout = (m0 + wm + i * 16 + ((qd & 2) << 2)) >> 3;
#pragma unroll
        for (int jj = 0; jj < 4; jj++) {
            const int col = n0 + wn + jj * 16 + rsel;
            const float bv = b1[col];
            float s = 0.f;
#pragma unroll
            for (int r = 0; r < 4; r++) s += w4[r] * fmaxf(acc[i][jj][r] + bv, 0.f);
            s += __shfl_xor(s, 16, 64);
            if ((qd & 1) == 0) pooledh[(size_t)Gout * 1024 + col] = f2b(s);
        }
    }
}

// ===== L4: gemm2 (192, swz) + kg pooling (4096) + h0p partials (48) =========
__global__ __launch_bounds__(256) void k_mega4(
    const bf16* __restrict__ pooledh, const bf16* __restrict__ w2t, bf16* __restrict__ pooled,
    const float* __restrict__ mlp_b2, const float* __restrict__ summask,
    const int* __restrict__ nodes, const float* __restrict__ nmask, const float* __restrict__ ent,
    const float* __restrict__ tv, const float* __restrict__ proj_w, float* __restrict__ hp) {
    int u = blockIdx.x;
    int tid = threadIdx.x;
    if (u < 192) {
        gemm_body<5>(pooledh, w2t, pooled, nullptr, mlp_b2, summask, 4096, 768, 1024, 6, 1, u);
        return;
    }
    u -= 192;
    if (u < 4096) {  // kg pooling
        int b = u >> 9, n = u & 511;
        int base = (((b << 10) + n) << 3);
        float a0 = 0.f, a1 = 0.f, a2 = 0.f;
        for (int m = 0; m < 8; m++) {
            float w = nmask[base + m];
            const float* row = ent + (size_t)nodes[base + m] * 768;
            a0 += w * row[tid];
            a1 += w * row[tid + 256];
            a2 += w * row[tid + 512];
        }
        bf16* dst = pooled + (size_t)((b << 10) + n) * 768;
        dst[tid] = f2b(a0);
        dst[tid + 256] = f2b(a1);
        dst[tid + 512] = f2b(a2);
        return;
    }
    u -= 4096;
    {  // h row0 partials: b=u/6, kc=u%6
        int b = u / 6, kc = u % 6;
        float acc = 0.f;
        for (int k = kc * 128; k < kc * 128 + 128; k++)
            acc += tv[b * 768 + k] * proj_w[k * 256 + tid];
        hp[(size_t)(b * 6 + kc) * 256 + tid] = acc;
    }
}

// ===== L5: folded np-GEMM (128, swz) + CSR scatter (512) ====================
__global__ __launch_bounds__(256) void k_mega5(
    const bf16* __restrict__ pooled, const bf16* __restrict__ wnpt,
    float* __restrict__ h, const float* __restrict__ proj_b,
    const int* __restrict__ edges, int* __restrict__ cursor, int* __restrict__ eord) {
    int u = blockIdx.x;
    int tid = threadIdx.x;
    if (u < 128) {
        gemm_body<4>(pooled, wnpt, nullptr, h, proj_b, nullptr, 8192, 256, 768, 2, 1, u);
        return;
    }
    u -= 128;
    {  // scatter
        int flat = u * 256 + tid;
        int b = flat >> 14, e = flat & (EE - 1);
        int d = edges[b * 2 * EE + EE + e];
        int pos = atomicAdd(&cursor[b * NNODES + d], 1);
        eord[b * EE + pos] = e;
    }
}

// --------------------- type-embed add + h row0 assembly + hbf + zero padding
__global__ __launch_bounds__(256) void k_tpe_add(const int* __restrict__ ntypes,
                                                 const float* __restrict__ tpe,
                                                 const float* __restrict__ hp,
                                                 const float* __restrict__ proj_b,
                                                 float* __restrict__ h, bf16* __restrict__ hbf) {
    int i = blockIdx.x;  // 0..1039
    int b = blockIdx.y;
    int c = threadIdx.x;
    size_t idx = ((size_t)b * HSTRIDE + i) * 256 + c;
    if (i < NNODES) {
        int t = ntypes[b * NNODES + i];
        float v;
        if (i == 0) {
            v = proj_b[c];
            for (int p = 0; p < 6; p++) v += hp[(size_t)(b * 6 + p) * 256 + c];
        } else {
            v = h[idx];
        }
        v += tpe[t * 256 + c];
        h[idx] = v;
        hbf[idx] = f2b(v);
    } else {
        h[idx] = 0.f;
        hbf[idx] = f2b(0.f);
    }
}

// ------------------------------------------------ GNN attention per dst node
__global__ __launch_bounds__(256) void k_gnn_node(const int* __restrict__ edges,
                                                  const int* __restrict__ etypes,
                                                  const int* __restrict__ offs,
                                                  const int* __restrict__ eord,
                                                  const float* __restrict__ etewe,
                                                  const bf16* __restrict__ qkv,
                                                  float* __restrict__ h, bf16* __restrict__ hbf) {
    int bid = blockIdx.x;
    int b = bid / NNODES, n = bid % NNODES;
    int o0 = offs[b * 1026 + n];
    int deg = offs[b * 1026 + n + 1] - o0;
    if (deg > MAXDEG) deg = MAXDEG;
    int tid = threadIdx.x, lane = tid & 63, wave = tid >> 6;
    __shared__ float qs[256];
    __shared__ float elog[MAXDEG][4];
    __shared__ int srcs[MAXDEG];
    __shared__ float smax[4], sden[4];
    __shared__ float vpart[4][256];
    size_t qbase = ((size_t)(b * HSTRIDE + n)) * 768;
    qs[tid] = b2f(qkv[qbase + tid]);
    __syncthreads();
    for (int i = wave; i < deg; i += 4) {
        int e = eord[b * EE + o0 + i];
        int src = edges[b * 2 * EE + e];
        int et = etypes[b * EE + e];
        const bf16* krow = qkv + ((size_t)(b * HSTRIDE + src)) * 768 + 256;
        const float* kerow = etewe + et * 256;
        float sum[4];
#pragma unroll
        for (int hh = 0; hh < 4; hh++) {
            float v = qs[hh * 64 + lane] * (b2f(krow[hh * 64 + lane]) + kerow[hh * 64 + lane]);
            for (int s = 32; s > 0; s >>= 1) v += __shfl_xor(v, s, 64);
            sum[hh] = v;
        }
        if (lane == 0) {
            srcs[i] = src;
#pragma unroll
            for (int hh = 0; hh < 4; hh++) elog[i][hh] = sum[hh] * 0.125f;
        }
    }
    __syncthreads();
    if (deg > 0) {
        int hh = wave;
        float m = -1e30f;
        for (int i = lane; i < deg; i += 64) m = fmaxf(m, elog[i][hh]);
        for (int s = 32; s > 0; s >>= 1) m = fmaxf(m, __shfl_xor(m, s, 64));
        float den = 0.f;
        for (int i = lane; i < deg; i += 64) den += expf(elog[i][hh] - m);
        for (int s = 32; s > 0; s >>= 1) den += __shfl_xor(den, s, 64);
        if (lane == 0) { smax[hh] = m; sden[hh] = den; }
    }
    __syncthreads();
    for (int i = tid; i < deg; i += 256) {
#pragma unroll
        for (int hh = 0; hh < 4; hh++)
            elog[i][hh] = expf(elog[i][hh] - smax[hh]) / (sden[hh] + 1e-9f);
    }
    __syncthreads();
    float a0 = 0.f, a1 = 0.f, a2 = 0.f, a3 = 0.f;
    const int hsel = lane >> 4;
    for (int i = wave; i < deg; i += 4) {
        float w = elog[i][hsel];
        const bf16* vrow = qkv + ((size_t)(b * HSTRIDE + srcs[i])) * 768 + 512 + lane * 4;
        ushort4 uu = *reinterpret_cast<const ushort4*>(vrow);
        a0 += w * bu2f(uu.x);
        a1 += w * bu2f(uu.y);
        a2 += w * bu2f(uu.z);
        a3 += w * bu2f(uu.w);
    }
    vpart[wave][lane * 4 + 0] = a0;
    vpart[wave][lane * 4 + 1] = a1;
    vpart[wave][lane * 4 + 2] = a2;
    vpart[wave][lane * 4 + 3] = a3;
    __syncthreads();
    float acc = vpart[0][tid] + vpart[1][tid] + vpart[2][tid] + vpart[3][tid];
    size_t hidx = ((size_t)(b * HSTRIDE + n)) * 256 + tid;
    float v = fmaxf(h[hidx] + acc, 0.f);
    h[hidx] = v;
    hbf[hidx] = f2b(v);
}

// ----------------------------------------------------------------- classifier
__global__ __launch_bounds__(256) void k_cls(const float* __restrict__ h,
                                             const float* __restrict__ tv,
                                             const float* __restrict__ weff,
                                             const float* __restrict__ beff,
                                             float* __restrict__ out) {
    int bc = blockIdx.x;
    int b = bc / 50, c = bc % 50;
    int tid = threadIdx.x;
    const float* we = weff + c * 1280;
    float acc = 0.f;
    for (int kk = tid; kk < 1280; kk += 256) {
        float f;
        if (kk < 256) f = h[((size_t)(b * HSTRIDE)) * 256 + kk];
        else if (kk < 512) f = h[((size_t)(b * HSTRIDE + 1 + c)) * 256 + (kk - 256)];
        else f = tv[b * 768 + (kk - 512)];
        acc += f * we[kk];
    }
    __shared__ float red[256];
    red[tid] = acc;
    __syncthreads();
    for (int s = 128; s > 0; s >>= 1) {
        if (tid < s) red[tid] += red[tid + s];
        __syncthreads();
    }
    if (tid == 0) out[b * 50 + c] = red[0] + beff[c];
}

// ======================================================================
extern "C" void kernel_launch(void* const* d_in, const int* in_sizes, int n_in,
                              void* d_out, int out_size, void* d_ws, size_t ws_size,
                              hipStream_t stream) {
    (void)in_sizes; (void)n_in; (void)out_size; (void)ws_size;
    const int* sentence       = (const int*)d_in[0];
    const float* mask         = (const float*)d_in[1];
    const int* nodes          = (const int*)d_in[2];
    const float* node_mask    = (const float*)d_in[3];
    const int* node_types     = (const int*)d_in[4];
    const int* edges          = (const int*)d_in[5];
    const int* edge_types     = (const int*)d_in[6];
    const float* word_embed   = (const float*)d_in[7];
    const float* entity_table = (const float*)d_in[8];
    const float* type_table   = (const float*)d_in[9];
    const float* mlp_w1       = (const float*)d_in[10];
    const float* mlp_b1       = (const float*)d_in[11];
    const float* mlp_w2       = (const float*)d_in[12];
    const float* mlp_b2       = (const float*)d_in[13];
    const float* ntw_w        = (const float*)d_in[14];
    const float* proj_w       = (const float*)d_in[15];
    const float* proj_b       = (const float*)d_in[16];
    const float* type_proj_w  = (const float*)d_in[17];
    const float* edge_tt      = (const float*)d_in[18];
    const float* gnn_wq       = (const float*)d_in[19];
    const float* gnn_wk       = (const float*)d_in[20];
    const float* gnn_wv       = (const float*)d_in[21];
    const float* gnn_we       = (const float*)d_in[22];
    const float* cls_w        = (const float*)d_in[23];
    const float* cls_b        = (const float*)d_in[24];
    const float* cls2_w       = (const float*)d_in[25];
    const float* cls2_b       = (const float*)d_in[26];

    char* ws = (char*)d_ws;
    size_t off = 0;
    auto alloc = [&](size_t bytes) {
        size_t r = off;
        off += (bytes + 255) & ~((size_t)255);
        return r;
    };
    bf16* w1t     = (bf16*)(ws + alloc((size_t)1024 * 768 * 2));
    bf16* w2t     = (bf16*)(ws + alloc((size_t)768 * 1024 * 2));
    bf16* ntwbf   = (bf16*)(ws + alloc((size_t)768 * 768 * 2));
    bf16* projt   = (bf16*)(ws + alloc((size_t)256 * 768 * 2));
    bf16* wnpt    = (bf16*)(ws + alloc((size_t)256 * 768 * 2));
    bf16* wqkvt   = (bf16*)(ws + alloc((size_t)2 * 768 * 256 * 2));
    float* tpe    = (float*)(ws + alloc((size_t)100 * 256 * 4));
    float* etewe  = (float*)(ws + alloc((size_t)2 * 50 * 256 * 4));
    float* weff   = (float*)(ws + alloc((size_t)50 * 1280 * 4));
    float* beff   = (float*)(ws + alloc(256));
    float* tv     = (float*)(ws + alloc((size_t)8 * 768 * 4));
    float* tvp    = (float*)(ws + alloc((size_t)64 * 768 * 4));
    float* msump  = (float*)(ws + alloc((size_t)64 * 4));
    float* hp     = (float*)(ws + alloc((size_t)48 * 256 * 4));
    float* summask= (float*)(ws + alloc((size_t)4096 * 4));
    int* counts   = (int*)(ws + alloc((size_t)8 * NNODES * 4));
    int* offs     = (int*)(ws + alloc((size_t)8 * 1026 * 4));
    int* cursor   = (int*)(ws + alloc((size_t)8 * NNODES * 4));
    int* eord     = (int*)(ws + alloc((size_t)8 * EE * 4));
    bf16* pooledh = (bf16*)(ws + alloc((size_t)4096 * 1024 * 2));
    bf16* pooled  = (bf16*)(ws + alloc((size_t)8192 * 768 * 2));
    float* h      = (float*)(ws + alloc((size_t)8 * HSTRIDE * 256 * 4));
    bf16* hbf     = (bf16*)(ws + alloc((size_t)8 * HSTRIDE * 256 * 2));
    bf16* qkv     = (bf16*)(ws + alloc((size_t)8 * HSTRIDE * 768 * 2));

    // L1: all independent preprocessing
    k_prep<<<3305, 256, 0, stream>>>(mlp_w1, mlp_w2, ntw_w, proj_w, gnn_wq, gnn_wk, gnn_wv,
                                     type_table, type_proj_w, edge_tt, gnn_we,
                                     cls_w, cls2_w, cls_b, cls2_b,
                                     sentence, mask, word_embed,
                                     w1t, w2t, ntwbf, projt, wqkvt,
                                     tpe, etewe, weff, beff, tvp, msump, counts);
    // L2: fold ntw@proj + tvred + summask + CSR count
    k_mid<<<548, 256, 0, stream>>>(projt, ntwbf, wnpt, tvp, msump, tv,
                                   node_mask, summask, edges, counts);
    // L3: MLP1 gather-GEMM + CSR scan
    k_mlp1_scan<<<2056, 256, 0, stream>>>(nodes, entity_table, w1t, mlp_b1, node_mask, pooledh,
                                          counts, offs, cursor);
    // L4: gemm2 + kg pooling + h-row0 partials
    k_mega4<<<4336, 256, 0, stream>>>(pooledh, w2t, pooled, mlp_b2, summask,
                                      nodes, node_mask, entity_table, tv, proj_w, hp);
    // L5: folded (ntw@proj) GEMM + CSR scatter
    k_mega5<<<640, 256, 0, stream>>>(pooled, wnpt, h, proj_b, edges, cursor, eord);
    // L6: type-embed add + assemble row0 + hbf + padding
    k_tpe_add<<<dim3(1040, 8), 256, 0, stream>>>(node_types, tpe, hp, proj_b, h, hbf);

    for (int l = 0; l < 2; l++) {
        gemm_bt<0><<<390, 256, 0, stream>>>(hbf, wqkvt + l * 196608, qkv, nullptr, nullptr,
                                            nullptr, 8320, 768, 256, 6, 0);
        k_gnn_node<<<8 * NNODES, 256, 0, stream>>>(edges, edge_types, offs, eord,
                                                   etewe + l * 12800, qkv, h, hbf);
    }
    k_cls<<<400, 256, 0, stream>>>(h, tv, weff, beff, (float*)d_out);
}

// Round 3
// 749.420 us; speedup vs baseline: 1.2635x; 1.0735x over previous
//
#include <hip/hip_runtime.h>
#include <hip/hip_bf16.h>
#include <stdint.h>

using bf16 = __hip_bfloat16;
typedef __attribute__((ext_vector_type(8))) short short8;
typedef __attribute__((ext_vector_type(4))) float f32x4;
typedef __attribute__((address_space(3))) unsigned int lds_u32;
typedef const __attribute__((address_space(1))) unsigned int gbl_u32;

#define HSTRIDE 1040
#define NNODES 1025
#define EE 16384
#define MAXDEG 192

__device__ __forceinline__ bf16 f2b(float x) { return __float2bfloat16(x); }
__device__ __forceinline__ float b2f(bf16 x) { return __bfloat162float(x); }
__device__ __forceinline__ float bu2f(unsigned short u) {
    union { unsigned int i; float f; } x;
    x.i = ((unsigned int)u) << 16;
    return x.f;
}

// mask index for logic row: row=(b*512+np)*8+m -> node_mask[(b*1024+512+np)*8+m]
__device__ __forceinline__ size_t midx(int row) {
    int G = row >> 3, m = row & 7, b = G >> 9;
    return (size_t)(G + 512 * (b + 1)) * 8 + m;
}

// ---------------------------------------------------------- shared GEMM body
// C = A @ Bt^T.  EPIL: 0=bf16 plain, 5=rowscale*bias -> bf16 remapped to
// pooled logic rows, 6=bias + type-embed add + h(f32) + hbf(bf16) remapped.
// swz=1: XCD-locality swizzle (requires (M/128)%8==0, range starts at bid 0)
template <int EPIL>
__device__ __forceinline__ void gemm_body(const bf16* __restrict__ A, const bf16* __restrict__ Bt,
                                          bf16* __restrict__ Cb, float* __restrict__ Cf,
                                          const float* __restrict__ bias,
                                          const float* __restrict__ smr,
                                          const int* __restrict__ nty,
                                          const float* __restrict__ tpe,
                                          bf16* __restrict__ hbf2,
                                          int M, int N, int K, int NT, int swz, int bid) {
    __shared__ bf16 As[128][32];
    __shared__ bf16 Bs[128][32];
    const int tid = threadIdx.x;
    int mt, nt;
    if (swz) {
        const int MT8 = (M >> 7) >> 3;
        const int j = bid >> 3;
        mt = (bid & 7) * MT8 + j / NT;
        nt = j - (j / NT) * NT;
    } else {
        mt = bid / NT;
        nt = bid - mt * NT;
    }
    const int m0 = mt << 7;
    const int n0 = nt << 7;
    const int lane = tid & 63;
    const int wave = tid >> 6;
    const int wm = (wave >> 1) << 6;
    const int wn = (wave & 1) << 6;
    const int rsel = lane & 15;
    const int qd = lane >> 4;
    f32x4 acc[4][4];
#pragma unroll
    for (int i = 0; i < 4; i++)
#pragma unroll
        for (int jj = 0; jj < 4; jj++) acc[i][jj] = (f32x4){0.f, 0.f, 0.f, 0.f};

    const int c0 = tid, r0 = c0 >> 2, kk0 = (c0 & 3) << 3;
    const int c1 = tid + 256, r1 = c1 >> 2, kk1 = (c1 & 3) << 3;

    for (int k0 = 0; k0 < K; k0 += 32) {
        __syncthreads();
        {
            const bf16* ga0 = A + (size_t)(m0 + r0) * K + (k0 + kk0);
            __builtin_amdgcn_global_load_lds((gbl_u32*)ga0, (lds_u32*)&As[r0][kk0], 16, 0, 0);
            const bf16* ga1 = A + (size_t)(m0 + r1) * K + (k0 + kk1);
            __builtin_amdgcn_global_load_lds((gbl_u32*)ga1, (lds_u32*)&As[r1][kk1], 16, 0, 0);
            const bf16* gb0 = Bt + (size_t)(n0 + r0) * K + (k0 + kk0);
            __builtin_amdgcn_global_load_lds((gbl_u32*)gb0, (lds_u32*)&Bs[r0][kk0], 16, 0, 0);
            const bf16* gb1 = Bt + (size_t)(n0 + r1) * K + (k0 + kk1);
            __builtin_amdgcn_global_load_lds((gbl_u32*)gb1, (lds_u32*)&Bs[r1][kk1], 16, 0, 0);
        }
        __syncthreads();
        short8 af[4], bfr[4];
#pragma unroll
        for (int i = 0; i < 4; i++) af[i] = *(const short8*)&As[wm + i * 16 + rsel][qd << 3];
#pragma unroll
        for (int jj = 0; jj < 4; jj++) bfr[jj] = *(const short8*)&Bs[wn + jj * 16 + rsel][qd << 3];
#pragma unroll
        for (int i = 0; i < 4; i++)
#pragma unroll
            for (int jj = 0; jj < 4; jj++)
                acc[i][jj] = __builtin_amdgcn_mfma_f32_16x16x32_bf16(af[i], bfr[jj], acc[i][jj], 0, 0, 0);
    }
#pragma unroll
    for (int i = 0; i < 4; i++) {
        const int rbase = m0 + wm + i * 16 + (qd << 2);
        float sm4[4];
        int t4[4];
        if constexpr (EPIL == 5) {
#pragma unroll
            for (int r = 0; r < 4; r++) sm4[r] = smr[rbase + r];
        }
        if constexpr (EPIL == 6) {
#pragma unroll
            for (int r = 0; r < 4; r++) {
                const int row = rbase + r;
                const int bb = row >> 10, nn2 = row & 1023;
                t4[r] = nty[bb * NNODES + 1 + nn2];
            }
        }
#pragma unroll
        for (int jj = 0; jj < 4; jj++) {
            const int col = n0 + wn + jj * 16 + rsel;
            float bv = 0.f;
            if constexpr (EPIL == 5 || EPIL == 6) bv = bias[col];
#pragma unroll
            for (int r = 0; r < 4; r++) {
                const int row = rbase + r;
                if constexpr (EPIL == 0) {
                    Cb[(size_t)row * N + col] = f2b(acc[i][jj][r]);
                } else if constexpr (EPIL == 6) {
                    const int bb = row >> 10, nn2 = row & 1023;
                    float v = acc[i][jj][r] + bv + tpe[t4[r] * 256 + col];
                    size_t ix = ((size_t)bb * HSTRIDE + 1 + nn2) * 256 + col;
                    Cf[ix] = v;
                    hbf2[ix] = f2b(v);
                } else {  // 5
                    const int dest = row + 512 * ((row >> 9) + 1);
                    Cb[(size_t)dest * N + col] = f2b(acc[i][jj][r] + sm4[r] * bv);
                }
            }
        }
    }
}

template <int EPIL>
__global__ __launch_bounds__(256) void gemm_bt(const bf16* __restrict__ A,
                                               const bf16* __restrict__ Bt,
                                               bf16* __restrict__ Cb, float* __restrict__ Cf,
                                               const float* __restrict__ bias,
                                               const float* __restrict__ smr,
                                               int M, int N, int K, int NT, int swz) {
    gemm_body<EPIL>(A, Bt, Cb, Cf, bias, smr, nullptr, nullptr, nullptr, M, N, K, NT, swz,
                    blockIdx.x);
}

// ------------------------------------------------- transpose helper (32x32)
__device__ __forceinline__ void tr_tile(const float* __restrict__ in, bf16* __restrict__ out,
                                        int R, int C, int gx, int gy, int tid,
                                        float (*tile)[33]) {
    int tx = tid & 31, ty = tid >> 5;  // 32 x 8
    int bx = gx * 32, by = gy * 32;
    for (int i = 0; i < 32; i += 8)
        tile[ty + i][tx] = in[(size_t)(by + ty + i) * C + bx + tx];
    __syncthreads();
    for (int i = 0; i < 32; i += 8)
        out[(size_t)(bx + ty + i) * R + by + tx] = f2b(tile[tx][ty + i]);
}

// ================= L1: all independent preprocessing in ONE kernel ==========
// gathers first (long poles), then transposes/small GEMMs/weff/textvec/zero
__global__ __launch_bounds__(256) void k_prep(
    const int* __restrict__ nodes, const float* __restrict__ node_mask,
    const float* __restrict__ ent, bf16* __restrict__ Abf, bf16* __restrict__ pooled,
    const float* __restrict__ mlp_w1, const float* __restrict__ mlp_w2,
    const float* __restrict__ ntw_w, const float* __restrict__ proj_w,
    const float* __restrict__ gnn_wq, const float* __restrict__ gnn_wk,
    const float* __restrict__ gnn_wv,
    const float* __restrict__ type_table, const float* __restrict__ type_proj_w,
    const float* __restrict__ edge_tt, const float* __restrict__ gnn_we,
    const float* __restrict__ cls_w, const float* __restrict__ cls2_w,
    const float* __restrict__ cls_b, const float* __restrict__ cls2_b,
    const int* __restrict__ sent, const float* __restrict__ maskp,
    const float* __restrict__ we,
    bf16* __restrict__ w1t, bf16* __restrict__ w2t, bf16* __restrict__ ntwbf,
    bf16* __restrict__ projt, bf16* __restrict__ wqkvt,
    float* __restrict__ tpe, float* __restrict__ etewe,
    float* __restrict__ weff, float* __restrict__ beff,
    float* __restrict__ tvp, float* __restrict__ msump, int* __restrict__ counts) {
    __shared__ float tile[32][33];
    int u = blockIdx.x;
    int tid = threadIdx.x;
    if (u < 4096) {  // gather logic-node entity rows -> Abf [32768][768] bf16
        int G = u;
        int r = tid >> 5, lane32 = tid & 31;
        int id = nodes[midx(G * 8 + r)];
        const float* src = ent + (size_t)id * 768;
        bf16* dst = Abf + (size_t)(G * 8 + r) * 768;
#pragma unroll
        for (int p = 0; p < 6; p++) {
            int col = p * 128 + lane32 * 4;
            float4 v = *(const float4*)(src + col);
            union { bf16 h[4]; uint2 q; } pk;
            pk.h[0] = f2b(v.x); pk.h[1] = f2b(v.y); pk.h[2] = f2b(v.z); pk.h[3] = f2b(v.w);
            *(uint2*)(dst + col) = pk.q;
        }
        return;
    }
    u -= 4096;
    if (u < 4096) {  // kg pooling (nodes 0..511 of each graph)
        int b = u >> 9, n = u & 511;
        int base = (((b << 10) + n) << 3);
        float a0 = 0.f, a1 = 0.f, a2 = 0.f;
        for (int m = 0; m < 8; m++) {
            float w = node_mask[base + m];
            const float* row = ent + (size_t)nodes[base + m] * 768;
            a0 += w * row[tid];
            a1 += w * row[tid + 256];
            a2 += w * row[tid + 512];
        }
        bf16* dst = pooled + (size_t)((b << 10) + n) * 768;
        dst[tid] = f2b(a0);
        dst[tid + 256] = f2b(a1);
        dst[tid + 512] = f2b(a2);
        return;
    }
    u -= 4096;
    if (u < 768) {  // mlp_w1 [768,1024] -> w1t [1024][768]
        tr_tile(mlp_w1, w1t, 768, 1024, u % 32, u / 32, tid, tile);
        return;
    }
    u -= 768;
    if (u < 768) {  // mlp_w2 [1024,768] -> w2t [768][1024]
        tr_tile(mlp_w2, w2t, 1024, 768, u % 24, u / 24, tid, tile);
        return;
    }
    u -= 768;
    if (u < 576) {  // ntw_w straight f32->bf16 copy
        int base = (u * 256 + tid) * 4;
        float4 v = *(const float4*)(ntw_w + base);
        union { bf16 h[4]; uint2 q; } pk;
        pk.h[0] = f2b(v.x); pk.h[1] = f2b(v.y); pk.h[2] = f2b(v.z); pk.h[3] = f2b(v.w);
        *(uint2*)(ntwbf + base) = pk.q;
        return;
    }
    u -= 576;
    if (u < 192) {  // proj_w [768,256] -> projt [256][768]
        tr_tile(proj_w, projt, 768, 256, u % 8, u / 8, tid, tile);
        return;
    }
    u -= 192;
    if (u < 384) {  // qkv weights: 6 x [256,256] transpose
        int z = u / 64, v = u % 64;
        int l = z / 3, which = z % 3;
        const float* in = (which == 0 ? gnn_wq : which == 1 ? gnn_wk : gnn_wv) + (size_t)l * 65536;
        bf16* o = wqkvt + (size_t)l * 196608 + (size_t)which * 65536;
        tr_tile(in, o, 256, 256, v % 8, v / 8, tid, tile);
        return;
    }
    u -= 384;
    if (u < 200) {  // small GEMMs: tpe(100) + etewe l0(50)/l1(50)
        const float* X;
        const float* W;
        float* out;
        if (u < 100) {
            X = type_table + u * 50; W = type_proj_w; out = tpe + u * 256;
        } else if (u < 150) {
            X = edge_tt + (u - 100) * 50; W = gnn_we; out = etewe + (u - 100) * 256;
        } else {
            X = edge_tt + (u - 150) * 50; W = gnn_we + 12800; out = etewe + 12800 + (u - 150) * 256;
        }
        float acc = 0.f;
        for (int k = 0; k < 50; k++) acc += X[k] * W[k * 256 + tid];
        out[tid] = acc;
        return;
    }
    u -= 200;
    if (u < 320) {  // weff: wave holds cls_w row in regs, loops 50 classes
        int wave = tid >> 6, lane = tid & 63;
        int k = u * 4 + wave;
        float wrow[12];
#pragma unroll
        for (int t = 0; t < 12; t++) wrow[t] = cls_w[(size_t)k * 768 + t * 64 + lane];
        for (int c = 0; c < 50; c++) {
            const float* c2 = cls2_w + c * 768;
            float acc = 0.f;
#pragma unroll
            for (int t = 0; t < 12; t++) acc += wrow[t] * c2[t * 64 + lane];
            for (int s = 32; s > 0; s >>= 1) acc += __shfl_xor(acc, s, 64);
            if (lane == 0) weff[c * 1280 + k] = acc;
        }
        if (u == 0) {
            float brow[12];
#pragma unroll
            for (int t = 0; t < 12; t++) brow[t] = cls_b[t * 64 + lane];
            for (int c = wave; c < 50; c += 4) {
                const float* c2 = cls2_w + c * 768;
                float acc = 0.f;
#pragma unroll
                for (int t = 0; t < 12; t++) acc += brow[t] * c2[t * 64 + lane];
                for (int s = 32; s > 0; s >>= 1) acc += __shfl_xor(acc, s, 64);
                if (lane == 0) beff[c] = acc + cls2_b[c];
            }
        }
        return;
    }
    u -= 320;
    if (u < 64) {  // textvec partials
        int b = u >> 3, ch = u & 7;
        float a0 = 0.f, a1 = 0.f, a2 = 0.f, ms = 0.f;
        for (int l = ch * 32; l < ch * 32 + 32; l++) {
            int w = sent[b * 256 + l];
            float mm = maskp[b * 256 + l];
            const float* row = we + (size_t)w * 768;
            a0 += mm * row[tid];
            a1 += mm * row[tid + 256];
            a2 += mm * row[tid + 512];
            ms += mm;
        }
        float* dst = tvp + (size_t)(b * 8 + ch) * 768;
        dst[tid] = a0;
        dst[tid + 256] = a1;
        dst[tid + 512] = a2;
        if (tid == 0) msump[b * 8 + ch] = ms;
        return;
    }
    u -= 64;
    {  // zero CSR counts (33 blocks)
        int i = u * 256 + tid;
        if (i < 8 * NNODES) counts[i] = 0;
    }
}

// ===== L2: fold-GEMM (W_np^T = projt @ ntwbf^T) + tvred + summask + count ===
__global__ __launch_bounds__(256) void k_mid(
    const bf16* __restrict__ projt, const bf16* __restrict__ ntwbf, bf16* __restrict__ wnpt,
    const float* __restrict__ tvp, const float* __restrict__ msump, float* __restrict__ tv,
    const float* __restrict__ node_mask, float* __restrict__ summask,
    const int* __restrict__ edges, int* __restrict__ counts) {
    int u = blockIdx.x;
    int tid = threadIdx.x;
    if (u < 12) {
        gemm_body<0>(projt, ntwbf, wnpt, nullptr, nullptr, nullptr, nullptr, nullptr, nullptr,
                     256, 768, 768, 6, 0, u);
        return;
    }
    u -= 12;
    if (u < 8) {  // tvred
        int b = u;
        float ms = 0.f;
        for (int p = 0; p < 8; p++) ms += msump[b * 8 + p];
        float inv = 1.f / (ms + 1e-9f);
        float a0 = 0.f, a1 = 0.f, a2 = 0.f;
        for (int p = 0; p < 8; p++) {
            const float* s = tvp + (size_t)(b * 8 + p) * 768;
            a0 += s[tid];
            a1 += s[tid + 256];
            a2 += s[tid + 512];
        }
        tv[b * 768 + tid] = a0 * inv;
        tv[b * 768 + tid + 256] = a1 * inv;
        tv[b * 768 + tid + 512] = a2 * inv;
        return;
    }
    u -= 8;
    if (u < 16) {  // summask
        int G = u * 256 + tid;
        if (G < 4096) {
            int b = G >> 9;
            const float* p = node_mask + (size_t)(G + 512 * (b + 1)) * 8;
            float s = 0.f;
            for (int m = 0; m < 8; m++) s += p[m];
            summask[G] = s;
        }
        return;
    }
    u -= 16;
    {  // CSR count (512 blocks)
        int flat = u * 256 + tid;
        int b = flat >> 14, e = flat & (EE - 1);
        int d = edges[b * 2 * EE + EE + e];
        atomicAdd(&counts[b * NNODES + d], 1);
    }
}

// ===== L3: clean GEMM1 on staged Abf (2048, XCD-swizzled) + CSR scan (8) ====
__global__ __launch_bounds__(256) void k_mlp1_scan(
    const bf16* __restrict__ Abf, const bf16* __restrict__ Bt, const float* __restrict__ b1,
    const float* __restrict__ node_mask, bf16* __restrict__ pooledh,
    const int* __restrict__ counts, int* __restrict__ offs, int* __restrict__ cursor) {
    __shared__ bf16 As[128][32];
    __shared__ bf16 Bs[128][32];
    __shared__ int tsum[256];
    const int tid = threadIdx.x;
    const int bid = blockIdx.x;
    if (bid >= 2048) {  // ---- scan ----
        int b = bid - 2048, t = tid;
        int beg = t * 5;
        int end = beg + 5;
        if (end > NNODES) end = NNODES;
        int cl[5];
        int s = 0;
        for (int i = beg; i < end; i++) {
            int v = counts[b * NNODES + i];
            cl[i - beg] = v;
            s += v;
        }
        tsum[t] = s;
        __syncthreads();
        for (int d = 1; d < 256; d <<= 1) {
            int v = tsum[t];
            int vo = (t >= d) ? tsum[t - d] : 0;
            __syncthreads();
            tsum[t] = v + vo;
            __syncthreads();
        }
        int run = (t == 0) ? 0 : tsum[t - 1];
        for (int i = beg; i < end; i++) {
            offs[b * 1026 + i] = run;
            cursor[b * NNODES + i] = run;
            run += cl[i - beg];
        }
        if (beg == NNODES) offs[b * 1026 + NNODES] = run;
        return;
    }
    // ---- clean GEMM1 + relu + mask-pool epilogue, XCD-swizzled ----
    const int j = bid >> 3;
    const int m0 = (((bid & 7) * 32) + (j >> 3)) << 7;
    const int n0 = (j & 7) << 7;
    const int lane = tid & 63;
    const int wave = tid >> 6;
    const int wm = (wave >> 1) << 6;
    const int wn = (wave & 1) << 6;
    const int rsel = lane & 15;
    const int qd = lane >> 4;
    const int K = 768;

    f32x4 acc[4][4];
#pragma unroll
    for (int i = 0; i < 4; i++)
#pragma unroll
        for (int jj = 0; jj < 4; jj++) acc[i][jj] = (f32x4){0.f, 0.f, 0.f, 0.f};

    const int c0 = tid, r0 = c0 >> 2, kk0 = (c0 & 3) << 3;
    const int c1 = tid + 256, r1 = c1 >> 2, kk1 = (c1 & 3) << 3;

    for (int k0 = 0; k0 < K; k0 += 32) {
        __syncthreads();
        const bf16* ga0 = Abf + (size_t)(m0 + r0) * K + (k0 + kk0);
        __builtin_amdgcn_global_load_lds((gbl_u32*)ga0, (lds_u32*)&As[r0][kk0], 16, 0, 0);
        const bf16* ga1 = Abf + (size_t)(m0 + r1) * K + (k0 + kk1);
        __builtin_amdgcn_global_load_lds((gbl_u32*)ga1, (lds_u32*)&As[r1][kk1], 16, 0, 0);
        const bf16* gb0 = Bt + (size_t)(n0 + r0) * K + (k0 + kk0);
        __builtin_amdgcn_global_load_lds((gbl_u32*)gb0, (lds_u32*)&Bs[r0][kk0], 16, 0, 0);
        const bf16* gb1 = Bt + (size_t)(n0 + r1) * K + (k0 + kk1);
        __builtin_amdgcn_global_load_lds((gbl_u32*)gb1, (lds_u32*)&Bs[r1][kk1], 16, 0, 0);
        __syncthreads();
        short8 af[4], bfr[4];
#pragma unroll
        for (int i = 0; i < 4; i++) af[i] = *(const short8*)&As[wm + i * 16 + rsel][qd << 3];
#pragma unroll
        for (int jj = 0; jj < 4; jj++) bfr[jj] = *(const short8*)&Bs[wn + jj * 16 + rsel][qd << 3];
#pragma unroll
        for (int i = 0; i < 4; i++)
#pragma unroll
            for (int jj = 0; jj < 4; jj++)
                acc[i][jj] = __builtin_amdgcn_mfma_f32_16x16x32_bf16(af[i], bfr[jj], acc[i][jj], 0, 0, 0);
    }
#pragma unroll
    for (int i = 0; i < 4; i++) {
        const int rbase = m0 + wm + i * 16 + (qd << 2);
        float w4[4];
#pragma unroll
        for (int r = 0; r < 4; r++) w4[r] = node_mask[midx(rbase + r)];
        const int Gout = (m0 + wm + i * 16 + ((qd & 2) << 2)) >> 3;
#pragma unroll
        for (int jj = 0; jj < 4; jj++) {
            const int col = n0 + wn + jj * 16 + rsel;
            const float bv = b1[col];
            float s = 0.f;
#pragma unroll
            for (int r = 0; r < 4; r++) s += w4[r] * fmaxf(acc[i][jj][r] + bv, 0.f);
            s += __shfl_xor(s, 16, 64);
            if ((qd & 1) == 0) pooledh[(size_t)Gout * 1024 + col] = f2b(s);
        }
    }
}

// ===== L4: gemm2 (192, swz) + h0p partials (48) + CSR scatter (512) =========
__global__ __launch_bounds__(256) void k_mega4(
    const bf16* __restrict__ pooledh, const bf16* __restrict__ w2t, bf16* __restrict__ pooled,
    const float* __restrict__ mlp_b2, const float* __restrict__ summask,
    const float* __restrict__ tv, const float* __restrict__ proj_w, float* __restrict__ hp,
    const int* __restrict__ edges, int* __restrict__ cursor, int* __restrict__ eord) {
    int u = blockIdx.x;
    int tid = threadIdx.x;
    if (u < 192) {
        gemm_body<5>(pooledh, w2t, pooled, nullptr, mlp_b2, summask, nullptr, nullptr, nullptr,
                     4096, 768, 1024, 6, 1, u);
        return;
    }
    u -= 192;
    if (u < 48) {  // h row0 partials: b=u/6, kc=u%6
        int b = u / 6, kc = u % 6;
        float acc = 0.f;
        for (int k = kc * 128; k < kc * 128 + 128; k++)
            acc += tv[b * 768 + k] * proj_w[k * 256 + tid];
        hp[(size_t)(b * 6 + kc) * 256 + tid] = acc;
        return;
    }
    u -= 48;
    {  // scatter (512)
        int flat = u * 256 + tid;
        int b = flat >> 14, e = flat & (EE - 1);
        int d = edges[b * 2 * EE + EE + e];
        int pos = atomicAdd(&cursor[b * NNODES + d], 1);
        eord[b * EE + pos] = e;
    }
}

// ===== L5: folded np-GEMM (128, swz, EPIL=6) + row0/pad assembly (128) ======
__global__ __launch_bounds__(256) void k_mega5(
    const bf16* __restrict__ pooled, const bf16* __restrict__ wnpt,
    float* __restrict__ h, bf16* __restrict__ hbf, const float* __restrict__ proj_b,
    const int* __restrict__ ntypes, const float* __restrict__ tpe,
    const float* __restrict__ hp) {
    int u = blockIdx.x;
    int tid = threadIdx.x;
    if (u < 128) {
        gemm_body<6>(pooled, wnpt, nullptr, h, proj_b, nullptr, ntypes, tpe, hbf,
                     8192, 256, 768, 2, 1, u);
        return;
    }
    u -= 128;
    {  // row0 + padding rows: b = u>>4, ii = u&15
        int b = u >> 4, ii = u & 15;
        int i = (ii == 0) ? 0 : 1024 + ii;  // 0, 1025..1039
        size_t idx = ((size_t)b * HSTRIDE + i) * 256 + tid;
        float v;
        if (ii == 0) {
            v = proj_b[tid];
            for (int p = 0; p < 6; p++) v += hp[(size_t)(b * 6 + p) * 256 + tid];
            v += tpe[ntypes[b * NNODES] * 256 + tid];
        } else {
            v = 0.f;
        }
        h[idx] = v;
        hbf[idx] = f2b(v);
    }
}

// ------------------------------------------------ GNN attention per dst node
// logits: 4x16-lane head-parallel dot (4 elems/lane, 4-deep shuffle)
__global__ __launch_bounds__(256) void k_gnn_node(const int* __restrict__ edges,
                                                  const int* __restrict__ etypes,
                                                  const int* __restrict__ offs,
                                                  const int* __restrict__ eord,
                                                  const float* __restrict__ etewe,
                                                  const bf16* __restrict__ qkv,
                                                  float* __restrict__ h, bf16* __restrict__ hbf) {
    int bid = blockIdx.x;
    int b = bid / NNODES, n = bid % NNODES;
    int o0 = offs[b * 1026 + n];
    int deg = offs[b * 1026 + n + 1] - o0;
    if (deg > MAXDEG) deg = MAXDEG;
    int tid = threadIdx.x, lane = tid & 63, wave = tid >> 6;
    __shared__ float qs[256];
    __shared__ float elog[MAXDEG][4];
    __shared__ int srcs[MAXDEG];
    __shared__ float smax[4], sden[4];
    __shared__ float vpart[4][256];
    size_t qbase = ((size_t)(b * HSTRIDE + n)) * 768;
    qs[tid] = b2f(qkv[qbase + tid]);
    __syncthreads();
    const int hq = lane >> 4;   // head (4 groups of 16 lanes)
    const int e4 = lane & 15;   // covers elems e4*4 .. e4*4+3
    float qreg[4];
#pragma unroll
    for (int j2 = 0; j2 < 4; j2++) qreg[j2] = qs[hq * 64 + e4 * 4 + j2];
    for (int i = wave; i < deg; i += 4) {
        int e = eord[b * EE + o0 + i];
        int src = edges[b * 2 * EE + e];
        int et = etypes[b * EE + e];
        const bf16* krow = qkv + ((size_t)(b * HSTRIDE + src)) * 768 + 256 + hq * 64 + e4 * 4;
        const float* kerow = etewe + et * 256 + hq * 64 + e4 * 4;
        ushort4 ku = *(const ushort4*)krow;
        float4 ke = *(const float4*)kerow;
        float v = qreg[0] * (bu2f(ku.x) + ke.x) + qreg[1] * (bu2f(ku.y) + ke.y) +
                  qreg[2] * (bu2f(ku.z) + ke.z) + qreg[3] * (bu2f(ku.w) + ke.w);
        v += __shfl_xor(v, 1, 64);
        v += __shfl_xor(v, 2, 64);
        v += __shfl_xor(v, 4, 64);
        v += __shfl_xor(v, 8, 64);
        if (e4 == 0) elog[i][hq] = v * 0.125f;
        if (lane == 0) srcs[i] = src;
    }
    __syncthreads();
    if (deg > 0) {  // 4 waves, one head each: lane-parallel max + denom
        int hh = wave;
        float m = -1e30f;
        for (int i = lane; i < deg; i += 64) m = fmaxf(m, elog[i][hh]);
        for (int s = 32; s > 0; s >>= 1) m = fmaxf(m, __shfl_xor(m, s, 64));
        float den = 0.f;
        for (int i = lane; i < deg; i += 64) den += expf(elog[i][hh] - m);
        for (int s = 32; s > 0; s >>= 1) den += __shfl_xor(den, s, 64);
        if (lane == 0) { smax[hh] = m; sden[hh] = den; }
    }
    __syncthreads();
    for (int i = tid; i < deg; i += 256) {
#pragma unroll
        for (int hh = 0; hh < 4; hh++)
            elog[i][hh] = expf(elog[i][hh] - smax[hh]) / (sden[hh] + 1e-9f);
    }
    __syncthreads();
    float a0 = 0.f, a1 = 0.f, a2 = 0.f, a3 = 0.f;
    const int hsel = lane >> 4;
    for (int i = wave; i < deg; i += 4) {
        float w = elog[i][hsel];
        const bf16* vrow = qkv + ((size_t)(b * HSTRIDE + srcs[i])) * 768 + 512 + lane * 4;
        ushort4 uu = *reinterpret_cast<const ushort4*>(vrow);
        a0 += w * bu2f(uu.x);
        a1 += w * bu2f(uu.y);
        a2 += w * bu2f(uu.z);
        a3 += w * bu2f(uu.w);
    }
    vpart[wave][lane * 4 + 0] = a0;
    vpart[wave][lane * 4 + 1] = a1;
    vpart[wave][lane * 4 + 2] = a2;
    vpart[wave][lane * 4 + 3] = a3;
    __syncthreads();
    float acc = vpart[0][tid] + vpart[1][tid] + vpart[2][tid] + vpart[3][tid];
    size_t hidx = ((size_t)(b * HSTRIDE + n)) * 256 + tid;
    float v = fmaxf(h[hidx] + acc, 0.f);
    h[hidx] = v;
    hbf[hidx] = f2b(v);
}

// ----------------------------------------------------------------- classifier
__global__ __launch_bounds__(256) void k_cls(const float* __restrict__ h,
                                             const float* __restrict__ tv,
                                             const float* __restrict__ weff,
                                             const float* __restrict__ beff,
                                             float* __restrict__ out) {
    int bc = blockIdx.x;
    int b = bc / 50, c = bc % 50;
    int tid = threadIdx.x;
    const float* we = weff + c * 1280;
    float acc = 0.f;
    for (int kk = tid; kk < 1280; kk += 256) {
        float f;
        if (kk < 256) f = h[((size_t)(b * HSTRIDE)) * 256 + kk];
        else if (kk < 512) f = h[((size_t)(b * HSTRIDE + 1 + c)) * 256 + (kk - 256)];
        else f = tv[b * 768 + (kk - 512)];
        acc += f * we[kk];
    }
    __shared__ float red[256];
    red[tid] = acc;
    __syncthreads();
    for (int s = 128; s > 0; s >>= 1) {
        if (tid < s) red[tid] += red[tid + s];
        __syncthreads();
    }
    if (tid == 0) out[b * 50 + c] = red[0] + beff[c];
}

// ======================================================================
extern "C" void kernel_launch(void* const* d_in, const int* in_sizes, int n_in,
                              void* d_out, int out_size, void* d_ws, size_t ws_size,
                              hipStream_t stream) {
    (void)in_sizes; (void)n_in; (void)out_size; (void)ws_size;
    const int* sentence       = (const int*)d_in[0];
    const float* mask         = (const float*)d_in[1];
    const int* nodes          = (const int*)d_in[2];
    const float* node_mask    = (const float*)d_in[3];
    const int* node_types     = (const int*)d_in[4];
    const int* edges          = (const int*)d_in[5];
    const int* edge_types     = (const int*)d_in[6];
    const float* word_embed   = (const float*)d_in[7];
    const float* entity_table = (const float*)d_in[8];
    const float* type_table   = (const float*)d_in[9];
    const float* mlp_w1       = (const float*)d_in[10];
    const float* mlp_b1       = (const float*)d_in[11];
    const float* mlp_w2       = (const float*)d_in[12];
    const float* mlp_b2       = (const float*)d_in[13];
    const float* ntw_w        = (const float*)d_in[14];
    const float* proj_w       = (const float*)d_in[15];
    const float* proj_b       = (const float*)d_in[16];
    const float* type_proj_w  = (const float*)d_in[17];
    const float* edge_tt      = (const float*)d_in[18];
    const float* gnn_wq       = (const float*)d_in[19];
    const float* gnn_wk       = (const float*)d_in[20];
    const float* gnn_wv       = (const float*)d_in[21];
    const float* gnn_we       = (const float*)d_in[22];
    const float* cls_w        = (const float*)d_in[23];
    const float* cls_b        = (const float*)d_in[24];
    const float* cls2_w       = (const float*)d_in[25];
    const float* cls2_b       = (const float*)d_in[26];

    char* ws = (char*)d_ws;
    size_t off = 0;
    auto alloc = [&](size_t bytes) {
        size_t r = off;
        off += (bytes + 255) & ~((size_t)255);
        return r;
    };
    bf16* w1t     = (bf16*)(ws + alloc((size_t)1024 * 768 * 2));
    bf16* w2t     = (bf16*)(ws + alloc((size_t)768 * 1024 * 2));
    bf16* ntwbf   = (bf16*)(ws + alloc((size_t)768 * 768 * 2));
    bf16* projt   = (bf16*)(ws + alloc((size_t)256 * 768 * 2));
    bf16* wnpt    = (bf16*)(ws + alloc((size_t)256 * 768 * 2));
    bf16* wqkvt   = (bf16*)(ws + alloc((size_t)2 * 768 * 256 * 2));
    float* tpe    = (float*)(ws + alloc((size_t)100 * 256 * 4));
    float* etewe  = (float*)(ws + alloc((size_t)2 * 50 * 256 * 4));
    float* weff   = (float*)(ws + alloc((size_t)50 * 1280 * 4));
    float* beff   = (float*)(ws + alloc(256));
    float* tv     = (float*)(ws + alloc((size_t)8 * 768 * 4));
    float* tvp    = (float*)(ws + alloc((size_t)64 * 768 * 4));
    float* msump  = (float*)(ws + alloc((size_t)64 * 4));
    float* hp     = (float*)(ws + alloc((size_t)48 * 256 * 4));
    float* summask= (float*)(ws + alloc((size_t)4096 * 4));
    int* counts   = (int*)(ws + alloc((size_t)8 * NNODES * 4));
    int* offs     = (int*)(ws + alloc((size_t)8 * 1026 * 4));
    int* cursor   = (int*)(ws + alloc((size_t)8 * NNODES * 4));
    int* eord     = (int*)(ws + alloc((size_t)8 * EE * 4));
    bf16* Abf     = (bf16*)(ws + alloc((size_t)32768 * 768 * 2));
    bf16* pooledh = (bf16*)(ws + alloc((size_t)4096 * 1024 * 2));
    bf16* pooled  = (bf16*)(ws + alloc((size_t)8192 * 768 * 2));
    float* h      = (float*)(ws + alloc((size_t)8 * HSTRIDE * 256 * 4));
    bf16* hbf     = (bf16*)(ws + alloc((size_t)8 * HSTRIDE * 256 * 2));
    bf16* qkv     = (bf16*)(ws + alloc((size_t)8 * HSTRIDE * 768 * 2));

    // L1: gathers + all independent preprocessing
    k_prep<<<11497, 256, 0, stream>>>(nodes, node_mask, entity_table, Abf, pooled,
                                      mlp_w1, mlp_w2, ntw_w, proj_w, gnn_wq, gnn_wk, gnn_wv,
                                      type_table, type_proj_w, edge_tt, gnn_we,
                                      cls_w, cls2_w, cls_b, cls2_b,
                                      sentence, mask, word_embed,
                                      w1t, w2t, ntwbf, projt, wqkvt,
                                      tpe, etewe, weff, beff, tvp, msump, counts);
    // L2: fold ntw@proj + tvred + summask + CSR count
    k_mid<<<548, 256, 0, stream>>>(projt, ntwbf, wnpt, tvp, msump, tv,
                                   node_mask, summask, edges, counts);
    // L3: clean GEMM1 + pooled epilogue + CSR scan
    k_mlp1_scan<<<2056, 256, 0, stream>>>(Abf, w1t, mlp_b1, node_mask, pooledh,
                                          counts, offs, cursor);
    // L4: gemm2 + h-row0 partials + CSR scatter
    k_mega4<<<752, 256, 0, stream>>>(pooledh, w2t, pooled, mlp_b2, summask,
                                     tv, proj_w, hp, edges, cursor, eord);
    // L5: folded np-GEMM with type-embed epilogue + row0/pad assembly
    k_mega5<<<256, 256, 0, stream>>>(pooled, wnpt, h, hbf, proj_b, node_types, tpe, hp);

    for (int l = 0; l < 2; l++) {
        gemm_bt<0><<<390, 256, 0, stream>>>(hbf, wqkvt + l * 196608, qkv, nullptr, nullptr,
                                            nullptr, 8320, 768, 256, 6, 0);
        k_gnn_node<<<8 * NNODES, 256, 0, stream>>>(edges, edge_types, offs, eord,
                                                   etewe + l * 12800, qkv, h, hbf);
    }
    k_cls<<<400, 256, 0, stream>>>(h, tv, weff, beff, (float*)d_out);
}

// Round 4
// 726.694 us; speedup vs baseline: 1.3030x; 1.0313x over previous
//
#include <hip/hip_runtime.h>
#include <hip/hip_bf16.h>
#include <stdint.h>

using bf16 = __hip_bfloat16;
typedef __attribute__((ext_vector_type(8))) short short8;
typedef __attribute__((ext_vector_type(4))) float f32x4;
typedef __attribute__((address_space(3))) unsigned int lds_u32;
typedef const __attribute__((address_space(1))) unsigned int gbl_u32;

#define HSTRIDE 1040
#define NNODES 1025
#define EE 16384
#define MAXDEG 192

__device__ __forceinline__ bf16 f2b(float x) { return __float2bfloat16(x); }
__device__ __forceinline__ float b2f(bf16 x) { return __bfloat162float(x); }
__device__ __forceinline__ float bu2f(unsigned short u) {
    union { unsigned int i; float f; } x;
    x.i = ((unsigned int)u) << 16;
    return x.f;
}

// mask index for logic row: row=(b*512+np)*8+m -> node_mask[(b*1024+512+np)*8+m]
__device__ __forceinline__ size_t midx(int row) {
    int G = row >> 3, m = row & 7, b = G >> 9;
    return (size_t)(G + 512 * (b + 1)) * 8 + m;
}

// ---------------------------------------------------------- shared GEMM body
// C = A @ Bt^T.  EPIL: 0=bf16 plain, 5=rowscale*bias -> bf16 remapped to
// pooled logic rows, 6=bias + type-embed add + h(f32) + hbf(bf16) remapped.
// swz=1: XCD-locality swizzle (requires (M/128)%8==0, range starts at bid 0)
template <int EPIL>
__device__ __forceinline__ void gemm_body(const bf16* __restrict__ A, const bf16* __restrict__ Bt,
                                          bf16* __restrict__ Cb, float* __restrict__ Cf,
                                          const float* __restrict__ bias,
                                          const float* __restrict__ smr,
                                          const int* __restrict__ nty,
                                          const float* __restrict__ tpe,
                                          bf16* __restrict__ hbf2,
                                          int M, int N, int K, int NT, int swz, int bid) {
    __shared__ bf16 As[128][32];
    __shared__ bf16 Bs[128][32];
    const int tid = threadIdx.x;
    int mt, nt;
    if (swz) {
        const int MT8 = (M >> 7) >> 3;
        const int j = bid >> 3;
        mt = (bid & 7) * MT8 + j / NT;
        nt = j - (j / NT) * NT;
    } else {
        mt = bid / NT;
        nt = bid - mt * NT;
    }
    const int m0 = mt << 7;
    const int n0 = nt << 7;
    const int lane = tid & 63;
    const int wave = tid >> 6;
    const int wm = (wave >> 1) << 6;
    const int wn = (wave & 1) << 6;
    const int rsel = lane & 15;
    const int qd = lane >> 4;
    f32x4 acc[4][4];
#pragma unroll
    for (int i = 0; i < 4; i++)
#pragma unroll
        for (int jj = 0; jj < 4; jj++) acc[i][jj] = (f32x4){0.f, 0.f, 0.f, 0.f};

    const int c0 = tid, r0 = c0 >> 2, kk0 = (c0 & 3) << 3;
    const int c1 = tid + 256, r1 = c1 >> 2, kk1 = (c1 & 3) << 3;

    for (int k0 = 0; k0 < K; k0 += 32) {
        __syncthreads();
        {
            const bf16* ga0 = A + (size_t)(m0 + r0) * K + (k0 + kk0);
            __builtin_amdgcn_global_load_lds((gbl_u32*)ga0, (lds_u32*)&As[r0][kk0], 16, 0, 0);
            const bf16* ga1 = A + (size_t)(m0 + r1) * K + (k0 + kk1);
            __builtin_amdgcn_global_load_lds((gbl_u32*)ga1, (lds_u32*)&As[r1][kk1], 16, 0, 0);
            const bf16* gb0 = Bt + (size_t)(n0 + r0) * K + (k0 + kk0);
            __builtin_amdgcn_global_load_lds((gbl_u32*)gb0, (lds_u32*)&Bs[r0][kk0], 16, 0, 0);
            const bf16* gb1 = Bt + (size_t)(n0 + r1) * K + (k0 + kk1);
            __builtin_amdgcn_global_load_lds((gbl_u32*)gb1, (lds_u32*)&Bs[r1][kk1], 16, 0, 0);
        }
        __syncthreads();
        short8 af[4], bfr[4];
#pragma unroll
        for (int i = 0; i < 4; i++) af[i] = *(const short8*)&As[wm + i * 16 + rsel][qd << 3];
#pragma unroll
        for (int jj = 0; jj < 4; jj++) bfr[jj] = *(const short8*)&Bs[wn + jj * 16 + rsel][qd << 3];
#pragma unroll
        for (int i = 0; i < 4; i++)
#pragma unroll
            for (int jj = 0; jj < 4; jj++)
                acc[i][jj] = __builtin_amdgcn_mfma_f32_16x16x32_bf16(af[i], bfr[jj], acc[i][jj], 0, 0, 0);
    }
#pragma unroll
    for (int i = 0; i < 4; i++) {
        const int rbase = m0 + wm + i * 16 + (qd << 2);
        float sm4[4];
        int t4[4];
        if constexpr (EPIL == 5) {
#pragma unroll
            for (int r = 0; r < 4; r++) sm4[r] = smr[rbase + r];
        }
        if constexpr (EPIL == 6) {
#pragma unroll
            for (int r = 0; r < 4; r++) {
                const int row = rbase + r;
                const int bb = row >> 10, nn2 = row & 1023;
                t4[r] = nty[bb * NNODES + 1 + nn2];
            }
        }
#pragma unroll
        for (int jj = 0; jj < 4; jj++) {
            const int col = n0 + wn + jj * 16 + rsel;
            float bv = 0.f;
            if constexpr (EPIL == 5 || EPIL == 6) bv = bias[col];
#pragma unroll
            for (int r = 0; r < 4; r++) {
                const int row = rbase + r;
                if constexpr (EPIL == 0) {
                    Cb[(size_t)row * N + col] = f2b(acc[i][jj][r]);
                } else if constexpr (EPIL == 6) {
                    const int bb = row >> 10, nn2 = row & 1023;
                    float v = acc[i][jj][r] + bv + tpe[t4[r] * 256 + col];
                    size_t ix = ((size_t)bb * HSTRIDE + 1 + nn2) * 256 + col;
                    Cf[ix] = v;
                    hbf2[ix] = f2b(v);
                } else {  // 5
                    const int dest = row + 512 * ((row >> 9) + 1);
                    Cb[(size_t)dest * N + col] = f2b(acc[i][jj][r] + sm4[r] * bv);
                }
            }
        }
    }
}

template <int EPIL>
__global__ __launch_bounds__(256) void gemm_bt(const bf16* __restrict__ A,
                                               const bf16* __restrict__ Bt,
                                               bf16* __restrict__ Cb, float* __restrict__ Cf,
                                               const float* __restrict__ bias,
                                               const float* __restrict__ smr,
                                               int M, int N, int K, int NT, int swz) {
    gemm_body<EPIL>(A, Bt, Cb, Cf, bias, smr, nullptr, nullptr, nullptr, M, N, K, NT, swz,
                    blockIdx.x);
}

// ------------------------------------------------- transpose helper (32x32)
__device__ __forceinline__ void tr_tile(const float* __restrict__ in, bf16* __restrict__ out,
                                        int R, int C, int gx, int gy, int tid,
                                        float (*tile)[33]) {
    int tx = tid & 31, ty = tid >> 5;  // 32 x 8
    int bx = gx * 32, by = gy * 32;
    for (int i = 0; i < 32; i += 8)
        tile[ty + i][tx] = in[(size_t)(by + ty + i) * C + bx + tx];
    __syncthreads();
    for (int i = 0; i < 32; i += 8)
        out[(size_t)(bx + ty + i) * R + by + tx] = f2b(tile[tx][ty + i]);
}

// ================= L1: all independent preprocessing in ONE kernel ==========
__global__ __launch_bounds__(256) void k_prep(
    const int* __restrict__ nodes, const float* __restrict__ node_mask,
    const float* __restrict__ ent, bf16* __restrict__ Abf, bf16* __restrict__ pooled,
    const float* __restrict__ mlp_w1, const float* __restrict__ mlp_w2,
    const float* __restrict__ ntw_w, const float* __restrict__ proj_w,
    const float* __restrict__ gnn_wq, const float* __restrict__ gnn_wk,
    const float* __restrict__ gnn_wv,
    const float* __restrict__ type_table, const float* __restrict__ type_proj_w,
    const float* __restrict__ edge_tt, const float* __restrict__ gnn_we,
    const float* __restrict__ cls_w, const float* __restrict__ cls2_w,
    const float* __restrict__ cls_b, const float* __restrict__ cls2_b,
    const int* __restrict__ sent, const float* __restrict__ maskp,
    const float* __restrict__ we,
    bf16* __restrict__ w1t, bf16* __restrict__ w2t, bf16* __restrict__ ntwbf,
    bf16* __restrict__ projt, bf16* __restrict__ wqkvt,
    float* __restrict__ tpe, float* __restrict__ etewe,
    float* __restrict__ weff, float* __restrict__ beff,
    float* __restrict__ tvp, float* __restrict__ msump, int* __restrict__ counts) {
    __shared__ float tile[32][33];
    int u = blockIdx.x;
    int tid = threadIdx.x;
    if (u < 4096) {  // gather logic-node entity rows -> Abf [32768][768] bf16
        int G = u;
        int r = tid >> 5, lane32 = tid & 31;
        int id = nodes[midx(G * 8 + r)];
        const float* src = ent + (size_t)id * 768;
        bf16* dst = Abf + (size_t)(G * 8 + r) * 768;
#pragma unroll
        for (int p = 0; p < 6; p++) {
            int col = p * 128 + lane32 * 4;
            float4 v = *(const float4*)(src + col);
            union { bf16 h[4]; uint2 q; } pk;
            pk.h[0] = f2b(v.x); pk.h[1] = f2b(v.y); pk.h[2] = f2b(v.z); pk.h[3] = f2b(v.w);
            *(uint2*)(dst + col) = pk.q;
        }
        return;
    }
    u -= 4096;
    if (u < 4096) {  // kg pooling (nodes 0..511 of each graph)
        int b = u >> 9, n = u & 511;
        int base = (((b << 10) + n) << 3);
        float a0 = 0.f, a1 = 0.f, a2 = 0.f;
        for (int m = 0; m < 8; m++) {
            float w = node_mask[base + m];
            const float* row = ent + (size_t)nodes[base + m] * 768;
            a0 += w * row[tid];
            a1 += w * row[tid + 256];
            a2 += w * row[tid + 512];
        }
        bf16* dst = pooled + (size_t)((b << 10) + n) * 768;
        dst[tid] = f2b(a0);
        dst[tid + 256] = f2b(a1);
        dst[tid + 512] = f2b(a2);
        return;
    }
    u -= 4096;
    if (u < 768) {  // mlp_w1 [768,1024] -> w1t [1024][768]
        tr_tile(mlp_w1, w1t, 768, 1024, u % 32, u / 32, tid, tile);
        return;
    }
    u -= 768;
    if (u < 768) {  // mlp_w2 [1024,768] -> w2t [768][1024]
        tr_tile(mlp_w2, w2t, 1024, 768, u % 24, u / 24, tid, tile);
        return;
    }
    u -= 768;
    if (u < 576) {  // ntw_w straight f32->bf16 copy
        int base = (u * 256 + tid) * 4;
        float4 v = *(const float4*)(ntw_w + base);
        union { bf16 h[4]; uint2 q; } pk;
        pk.h[0] = f2b(v.x); pk.h[1] = f2b(v.y); pk.h[2] = f2b(v.z); pk.h[3] = f2b(v.w);
        *(uint2*)(ntwbf + base) = pk.q;
        return;
    }
    u -= 576;
    if (u < 192) {  // proj_w [768,256] -> projt [256][768]
        tr_tile(proj_w, projt, 768, 256, u % 8, u / 8, tid, tile);
        return;
    }
    u -= 192;
    if (u < 384) {  // qkv weights: 6 x [256,256] transpose
        int z = u / 64, v = u % 64;
        int l = z / 3, which = z % 3;
        const float* in = (which == 0 ? gnn_wq : which == 1 ? gnn_wk : gnn_wv) + (size_t)l * 65536;
        bf16* o = wqkvt + (size_t)l * 196608 + (size_t)which * 65536;
        tr_tile(in, o, 256, 256, v % 8, v / 8, tid, tile);
        return;
    }
    u -= 384;
    if (u < 200) {  // small GEMMs: tpe(100) + etewe l0(50)/l1(50)
        const float* X;
        const float* W;
        float* out;
        if (u < 100) {
            X = type_table + u * 50; W = type_proj_w; out = tpe + u * 256;
        } else if (u < 150) {
            X = edge_tt + (u - 100) * 50; W = gnn_we; out = etewe + (u - 100) * 256;
        } else {
            X = edge_tt + (u - 150) * 50; W = gnn_we + 12800; out = etewe + 12800 + (u - 150) * 256;
        }
        float acc = 0.f;
        for (int k = 0; k < 50; k++) acc += X[k] * W[k * 256 + tid];
        out[tid] = acc;
        return;
    }
    u -= 200;
    if (u < 320) {  // weff: wave holds cls_w row in regs, loops 50 classes
        int wave = tid >> 6, lane = tid & 63;
        int k = u * 4 + wave;
        float wrow[12];
#pragma unroll
        for (int t = 0; t < 12; t++) wrow[t] = cls_w[(size_t)k * 768 + t * 64 + lane];
        for (int c = 0; c < 50; c++) {
            const float* c2 = cls2_w + c * 768;
            float acc = 0.f;
#pragma unroll
            for (int t = 0; t < 12; t++) acc += wrow[t] * c2[t * 64 + lane];
            for (int s = 32; s > 0; s >>= 1) acc += __shfl_xor(acc, s, 64);
            if (lane == 0) weff[c * 1280 + k] = acc;
        }
        if (u == 0) {
            float brow[12];
#pragma unroll
            for (int t = 0; t < 12; t++) brow[t] = cls_b[t * 64 + lane];
            for (int c = wave; c < 50; c += 4) {
                const float* c2 = cls2_w + c * 768;
                float acc = 0.f;
#pragma unroll
                for (int t = 0; t < 12; t++) acc += brow[t] * c2[t * 64 + lane];
                for (int s = 32; s > 0; s >>= 1) acc += __shfl_xor(acc, s, 64);
                if (lane == 0) beff[c] = acc + cls2_b[c];
            }
        }
        return;
    }
    u -= 320;
    if (u < 64) {  // textvec partials
        int b = u >> 3, ch = u & 7;
        float a0 = 0.f, a1 = 0.f, a2 = 0.f, ms = 0.f;
        for (int l = ch * 32; l < ch * 32 + 32; l++) {
            int w = sent[b * 256 + l];
            float mm = maskp[b * 256 + l];
            const float* row = we + (size_t)w * 768;
            a0 += mm * row[tid];
            a1 += mm * row[tid + 256];
            a2 += mm * row[tid + 512];
            ms += mm;
        }
        float* dst = tvp + (size_t)(b * 8 + ch) * 768;
        dst[tid] = a0;
        dst[tid + 256] = a1;
        dst[tid + 512] = a2;
        if (tid == 0) msump[b * 8 + ch] = ms;
        return;
    }
    u -= 64;
    {  // zero CSR counts (33 blocks)
        int i = u * 256 + tid;
        if (i < 8 * NNODES) counts[i] = 0;
    }
}

// ===== L2: fold-GEMM (W_np^T = projt @ ntwbf^T) + tvred + summask + count ===
__global__ __launch_bounds__(256) void k_mid(
    const bf16* __restrict__ projt, const bf16* __restrict__ ntwbf, bf16* __restrict__ wnpt,
    const float* __restrict__ tvp, const float* __restrict__ msump, float* __restrict__ tv,
    const float* __restrict__ node_mask, float* __restrict__ summask,
    const int* __restrict__ edges, int* __restrict__ counts) {
    int u = blockIdx.x;
    int tid = threadIdx.x;
    if (u < 12) {
        gemm_body<0>(projt, ntwbf, wnpt, nullptr, nullptr, nullptr, nullptr, nullptr, nullptr,
                     256, 768, 768, 6, 0, u);
        return;
    }
    u -= 12;
    if (u < 8) {  // tvred
        int b = u;
        float ms = 0.f;
        for (int p = 0; p < 8; p++) ms += msump[b * 8 + p];
        float inv = 1.f / (ms + 1e-9f);
        float a0 = 0.f, a1 = 0.f, a2 = 0.f;
        for (int p = 0; p < 8; p++) {
            const float* s = tvp + (size_t)(b * 8 + p) * 768;
            a0 += s[tid];
            a1 += s[tid + 256];
            a2 += s[tid + 512];
        }
        tv[b * 768 + tid] = a0 * inv;
        tv[b * 768 + tid + 256] = a1 * inv;
        tv[b * 768 + tid + 512] = a2 * inv;
        return;
    }
    u -= 8;
    if (u < 16) {  // summask
        int G = u * 256 + tid;
        if (G < 4096) {
            int b = G >> 9;
            const float* p = node_mask + (size_t)(G + 512 * (b + 1)) * 8;
            float s = 0.f;
            for (int m = 0; m < 8; m++) s += p[m];
            summask[G] = s;
        }
        return;
    }
    u -= 16;
    {  // CSR count (512 blocks)
        int flat = u * 256 + tid;
        int b = flat >> 14, e = flat & (EE - 1);
        int d = edges[b * 2 * EE + EE + e];
        atomicAdd(&counts[b * NNODES + d], 1);
    }
}

// ===== L3: clean GEMM1 on staged Abf (2048, XCD-swizzled) + CSR scan (8) ====
__global__ __launch_bounds__(256) void k_mlp1_scan(
    const bf16* __restrict__ Abf, const bf16* __restrict__ Bt, const float* __restrict__ b1,
    const float* __restrict__ node_mask, bf16* __restrict__ pooledh,
    const int* __restrict__ counts, int* __restrict__ offs, int* __restrict__ cursor) {
    __shared__ bf16 As[128][32];
    __shared__ bf16 Bs[128][32];
    __shared__ int tsum[256];
    const int tid = threadIdx.x;
    const int bid = blockIdx.x;
    if (bid >= 2048) {  // ---- scan ----
        int b = bid - 2048, t = tid;
        int beg = t * 5;
        int end = beg + 5;
        if (end > NNODES) end = NNODES;
        int cl[5];
        int s = 0;
        for (int i = beg; i < end; i++) {
            int v = counts[b * NNODES + i];
            cl[i - beg] = v;
            s += v;
        }
        tsum[t] = s;
        __syncthreads();
        for (int d = 1; d < 256; d <<= 1) {
            int v = tsum[t];
            int vo = (t >= d) ? tsum[t - d] : 0;
            __syncthreads();
            tsum[t] = v + vo;
            __syncthreads();
        }
        int run = (t == 0) ? 0 : tsum[t - 1];
        for (int i = beg; i < end; i++) {
            offs[b * 1026 + i] = run;
            cursor[b * NNODES + i] = run;
            run += cl[i - beg];
        }
        if (beg == NNODES) offs[b * 1026 + NNODES] = run;
        return;
    }
    // ---- clean GEMM1 + relu + mask-pool epilogue, XCD-swizzled ----
    const int j = bid >> 3;
    const int m0 = (((bid & 7) * 32) + (j >> 3)) << 7;
    const int n0 = (j & 7) << 7;
    const int lane = tid & 63;
    const int wave = tid >> 6;
    const int wm = (wave >> 1) << 6;
    const int wn = (wave & 1) << 6;
    const int rsel = lane & 15;
    const int qd = lane >> 4;
    const int K = 768;

    f32x4 acc[4][4];
#pragma unroll
    for (int i = 0; i < 4; i++)
#pragma unroll
        for (int jj = 0; jj < 4; jj++) acc[i][jj] = (f32x4){0.f, 0.f, 0.f, 0.f};

    const int c0 = tid, r0 = c0 >> 2, kk0 = (c0 & 3) << 3;
    const int c1 = tid + 256, r1 = c1 >> 2, kk1 = (c1 & 3) << 3;

    for (int k0 = 0; k0 < K; k0 += 32) {
        __syncthreads();
        const bf16* ga0 = Abf + (size_t)(m0 + r0) * K + (k0 + kk0);
        __builtin_amdgcn_global_load_lds((gbl_u32*)ga0, (lds_u32*)&As[r0][kk0], 16, 0, 0);
        const bf16* ga1 = Abf + (size_t)(m0 + r1) * K + (k0 + kk1);
        __builtin_amdgcn_global_load_lds((gbl_u32*)ga1, (lds_u32*)&As[r1][kk1], 16, 0, 0);
        const bf16* gb0 = Bt + (size_t)(n0 + r0) * K + (k0 + kk0);
        __builtin_amdgcn_global_load_lds((gbl_u32*)gb0, (lds_u32*)&Bs[r0][kk0], 16, 0, 0);
        const bf16* gb1 = Bt + (size_t)(n0 + r1) * K + (k0 + kk1);
        __builtin_amdgcn_global_load_lds((gbl_u32*)gb1, (lds_u32*)&Bs[r1][kk1], 16, 0, 0);
        __syncthreads();
        short8 af[4], bfr[4];
#pragma unroll
        for (int i = 0; i < 4; i++) af[i] = *(const short8*)&As[wm + i * 16 + rsel][qd << 3];
#pragma unroll
        for (int jj = 0; jj < 4; jj++) bfr[jj] = *(const short8*)&Bs[wn + jj * 16 + rsel][qd << 3];
#pragma unroll
        for (int i = 0; i < 4; i++)
#pragma unroll
            for (int jj = 0; jj < 4; jj++)
                acc[i][jj] = __builtin_amdgcn_mfma_f32_16x16x32_bf16(af[i], bfr[jj], acc[i][jj], 0, 0, 0);
    }
#pragma unroll
    for (int i = 0; i < 4; i++) {
        const int rbase = m0 + wm + i * 16 + (qd << 2);
        float w4[4];
#pragma unroll
        for (int r = 0; r < 4; r++) w4[r] = node_mask[midx(rbase + r)];
        const int Gout = (m0 + wm + i * 16 + ((qd & 2) << 2)) >> 3;
#pragma unroll
        for (int jj = 0; jj < 4; jj++) {
            const int col = n0 + wn + jj * 16 + rsel;
            const float bv = b1[col];
            float s = 0.f;
#pragma unroll
            for (int r = 0; r < 4; r++) s += w4[r] * fmaxf(acc[i][jj][r] + bv, 0.f);
            s += __shfl_xor(s, 16, 64);
            if ((qd & 1) == 0) pooledh[(size_t)Gout * 1024 + col] = f2b(s);
        }
    }
}

// ===== L4: gemm2 (192, swz) + h0p partials (48) + CSR scatter (512) =========
__global__ __launch_bounds__(256) void k_mega4(
    const bf16* __restrict__ pooledh, const bf16* __restrict__ w2t, bf16* __restrict__ pooled,
    const float* __restrict__ mlp_b2, const float* __restrict__ summask,
    const float* __restrict__ tv, const float* __restrict__ proj_w, float* __restrict__ hp,
    const int* __restrict__ edges, int* __restrict__ cursor, int* __restrict__ eord) {
    int u = blockIdx.x;
    int tid = threadIdx.x;
    if (u < 192) {
        gemm_body<5>(pooledh, w2t, pooled, nullptr, mlp_b2, summask, nullptr, nullptr, nullptr,
                     4096, 768, 1024, 6, 1, u);
        return;
    }
    u -= 192;
    if (u < 48) {  // h row0 partials: b=u/6, kc=u%6
        int b = u / 6, kc = u % 6;
        float acc = 0.f;
        for (int k = kc * 128; k < kc * 128 + 128; k++)
            acc += tv[b * 768 + k] * proj_w[k * 256 + tid];
        hp[(size_t)(b * 6 + kc) * 256 + tid] = acc;
        return;
    }
    u -= 48;
    {  // scatter (512)
        int flat = u * 256 + tid;
        int b = flat >> 14, e = flat & (EE - 1);
        int d = edges[b * 2 * EE + EE + e];
        int pos = atomicAdd(&cursor[b * NNODES + d], 1);
        eord[b * EE + pos] = e;
    }
}

// ===== L5: folded np-GEMM (128, swz, EPIL=6) + row0/pad assembly (128) ======
__global__ __launch_bounds__(256) void k_mega5(
    const bf16* __restrict__ pooled, const bf16* __restrict__ wnpt,
    float* __restrict__ h, bf16* __restrict__ hbf, const float* __restrict__ proj_b,
    const int* __restrict__ ntypes, const float* __restrict__ tpe,
    const float* __restrict__ hp) {
    int u = blockIdx.x;
    int tid = threadIdx.x;
    if (u < 128) {
        gemm_body<6>(pooled, wnpt, nullptr, h, proj_b, nullptr, ntypes, tpe, hbf,
                     8192, 256, 768, 2, 1, u);
        return;
    }
    u -= 128;
    {  // row0 + padding rows: b = u>>4, ii = u&15
        int b = u >> 4, ii = u & 15;
        int i = (ii == 0) ? 0 : 1024 + ii;  // 0, 1025..1039
        size_t idx = ((size_t)b * HSTRIDE + i) * 256 + tid;
        float v;
        if (ii == 0) {
            v = proj_b[tid];
            for (int p = 0; p < 6; p++) v += hp[(size_t)(b * 6 + p) * 256 + tid];
            v += tpe[ntypes[b * NNODES] * 256 + tid];
        } else {
            v = 0.f;
        }
        h[idx] = v;
        hbf[idx] = f2b(v);
    }
}

// ------------------------------------------------ GNN attention per dst node
// b-major XCD pinning: b = bid&7 -> graph b lives on XCD b (qkv L2-resident).
// Edge metadata prefetched coalesced into LDS; exp/invden folded into agg.
__global__ __launch_bounds__(256) void k_gnn_node(const int* __restrict__ edges,
                                                  const int* __restrict__ etypes,
                                                  const int* __restrict__ offs,
                                                  const int* __restrict__ eord,
                                                  const float* __restrict__ etewe,
                                                  const bf16* __restrict__ qkv,
                                                  float* __restrict__ h, bf16* __restrict__ hbf) {
    int bid = blockIdx.x;
    int b = bid & 7, n = bid >> 3;  // XCD x <- graph x (round-robin dispatch)
    int o0 = offs[b * 1026 + n];
    int deg = offs[b * 1026 + n + 1] - o0;
    if (deg > MAXDEG) deg = MAXDEG;
    int tid = threadIdx.x, lane = tid & 63, wave = tid >> 6;
    __shared__ float qs[256];
    __shared__ float elog[MAXDEG][4];
    __shared__ int srcs[MAXDEG];
    __shared__ int ets[MAXDEG];
    __shared__ float smax[4], sinv[4];
    __shared__ float vpart[4][256];
    size_t qbase = ((size_t)(b * HSTRIDE + n)) * 768;
    qs[tid] = b2f(qkv[qbase + tid]);
    // coalesced edge-metadata prefetch (breaks dependent-load chain)
    for (int i = tid; i < deg; i += 256) {
        int e = eord[b * EE + o0 + i];
        srcs[i] = edges[b * 2 * EE + e];
        ets[i] = etypes[b * EE + e];
    }
    __syncthreads();
    const int hq = lane >> 4;   // head (4 groups of 16 lanes)
    const int e4 = lane & 15;   // covers elems e4*4 .. e4*4+3
    float qreg[4];
#pragma unroll
    for (int j2 = 0; j2 < 4; j2++) qreg[j2] = qs[hq * 64 + e4 * 4 + j2];
    for (int i = wave; i < deg; i += 4) {
        int src = srcs[i];
        int et = ets[i];
        const bf16* krow = qkv + ((size_t)(b * HSTRIDE + src)) * 768 + 256 + hq * 64 + e4 * 4;
        const float* kerow = etewe + et * 256 + hq * 64 + e4 * 4;
        ushort4 ku = *(const ushort4*)krow;
        float4 ke = *(const float4*)kerow;
        float v = qreg[0] * (bu2f(ku.x) + ke.x) + qreg[1] * (bu2f(ku.y) + ke.y) +
                  qreg[2] * (bu2f(ku.z) + ke.z) + qreg[3] * (bu2f(ku.w) + ke.w);
        v += __shfl_xor(v, 1, 64);
        v += __shfl_xor(v, 2, 64);
        v += __shfl_xor(v, 4, 64);
        v += __shfl_xor(v, 8, 64);
        if (e4 == 0) elog[i][hq] = v * 0.125f;
    }
    __syncthreads();
    if (deg > 0) {  // 4 waves, one head each: lane-parallel max + denom
        int hh = wave;
        float m = -1e30f;
        for (int i = lane; i < deg; i += 64) m = fmaxf(m, elog[i][hh]);
        for (int s = 32; s > 0; s >>= 1) m = fmaxf(m, __shfl_xor(m, s, 64));
        float den = 0.f;
        for (int i = lane; i < deg; i += 64) den += expf(elog[i][hh] - m);
        for (int s = 32; s > 0; s >>= 1) den += __shfl_xor(den, s, 64);
        if (lane == 0) { smax[hh] = m; sinv[hh] = 1.f / (den + 1e-9f); }
    }
    __syncthreads();
    // aggregation: wave w takes edges w::4, lane covers cols lane*4..+3;
    // exp+invden folded in (redundant exps are cheap VALU)
    float a0 = 0.f, a1 = 0.f, a2 = 0.f, a3 = 0.f;
    const int hsel = lane >> 4;
    const float mh = smax[hsel], ih = sinv[hsel];
    for (int i = wave; i < deg; i += 4) {
        float w = expf(elog[i][hsel] - mh) * ih;
        const bf16* vrow = qkv + ((size_t)(b * HSTRIDE + srcs[i])) * 768 + 512 + lane * 4;
        ushort4 uu = *reinterpret_cast<const ushort4*>(vrow);
        a0 += w * bu2f(uu.x);
        a1 += w * bu2f(uu.y);
        a2 += w * bu2f(uu.z);
        a3 += w * bu2f(uu.w);
    }
    vpart[wave][lane * 4 + 0] = a0;
    vpart[wave][lane * 4 + 1] = a1;
    vpart[wave][lane * 4 + 2] = a2;
    vpart[wave][lane * 4 + 3] = a3;
    __syncthreads();
    float acc = vpart[0][tid] + vpart[1][tid] + vpart[2][tid] + vpart[3][tid];
    size_t hidx = ((size_t)(b * HSTRIDE + n)) * 256 + tid;
    float v = fmaxf(h[hidx] + acc, 0.f);
    h[hidx] = v;
    hbf[hidx] = f2b(v);
}

// ----------------------------------------------------------------- classifier
__global__ __launch_bounds__(256) void k_cls(const float* __restrict__ h,
                                             const float* __restrict__ tv,
                                             const float* __restrict__ weff,
                                             const float* __restrict__ beff,
                                             float* __restrict__ out) {
    int bc = blockIdx.x;
    int b = bc / 50, c = bc % 50;
    int tid = threadIdx.x;
    const float* we = weff + c * 1280;
    float acc = 0.f;
    for (int kk = tid; kk < 1280; kk += 256) {
        float f;
        if (kk < 256) f = h[((size_t)(b * HSTRIDE)) * 256 + kk];
        else if (kk < 512) f = h[((size_t)(b * HSTRIDE + 1 + c)) * 256 + (kk - 256)];
        else f = tv[b * 768 + (kk - 512)];
        acc += f * we[kk];
    }
    __shared__ float red[256];
    red[tid] = acc;
    __syncthreads();
    for (int s = 128; s > 0; s >>= 1) {
        if (tid < s) red[tid] += red[tid + s];
        __syncthreads();
    }
    if (tid == 0) out[b * 50 + c] = red[0] + beff[c];
}

// ======================================================================
extern "C" void kernel_launch(void* const* d_in, const int* in_sizes, int n_in,
                              void* d_out, int out_size, void* d_ws, size_t ws_size,
                              hipStream_t stream) {
    (void)in_sizes; (void)n_in; (void)out_size; (void)ws_size;
    const int* sentence       = (const int*)d_in[0];
    const float* mask         = (const float*)d_in[1];
    const int* nodes          = (const int*)d_in[2];
    const float* node_mask    = (const float*)d_in[3];
    const int* node_types     = (const int*)d_in[4];
    const int* edges          = (const int*)d_in[5];
    const int* edge_types     = (const int*)d_in[6];
    const float* word_embed   = (const float*)d_in[7];
    const float* entity_table = (const float*)d_in[8];
    const float* type_table   = (const float*)d_in[9];
    const float* mlp_w1       = (const float*)d_in[10];
    const float* mlp_b1       = (const float*)d_in[11];
    const float* mlp_w2       = (const float*)d_in[12];
    const float* mlp_b2       = (const float*)d_in[13];
    const float* ntw_w        = (const float*)d_in[14];
    const float* proj_w       = (const float*)d_in[15];
    const float* proj_b       = (const float*)d_in[16];
    const float* type_proj_w  = (const float*)d_in[17];
    const float* edge_tt      = (const float*)d_in[18];
    const float* gnn_wq       = (const float*)d_in[19];
    const float* gnn_wk       = (const float*)d_in[20];
    const float* gnn_wv       = (const float*)d_in[21];
    const float* gnn_we       = (const float*)d_in[22];
    const float* cls_w        = (const float*)d_in[23];
    const float* cls_b        = (const float*)d_in[24];
    const float* cls2_w       = (const float*)d_in[25];
    const float* cls2_b       = (const float*)d_in[26];

    char* ws = (char*)d_ws;
    size_t off = 0;
    auto alloc = [&](size_t bytes) {
        size_t r = off;
        off += (bytes + 255) & ~((size_t)255);
        return r;
    };
    bf16* w1t     = (bf16*)(ws + alloc((size_t)1024 * 768 * 2));
    bf16* w2t     = (bf16*)(ws + alloc((size_t)768 * 1024 * 2));
    bf16* ntwbf   = (bf16*)(ws + alloc((size_t)768 * 768 * 2));
    bf16* projt   = (bf16*)(ws + alloc((size_t)256 * 768 * 2));
    bf16* wnpt    = (bf16*)(ws + alloc((size_t)256 * 768 * 2));
    bf16* wqkvt   = (bf16*)(ws + alloc((size_t)2 * 768 * 256 * 2));
    float* tpe    = (float*)(ws + alloc((size_t)100 * 256 * 4));
    float* etewe  = (float*)(ws + alloc((size_t)2 * 50 * 256 * 4));
    float* weff   = (float*)(ws + alloc((size_t)50 * 1280 * 4));
    float* beff   = (float*)(ws + alloc(256));
    float* tv     = (float*)(ws + alloc((size_t)8 * 768 * 4));
    float* tvp    = (float*)(ws + alloc((size_t)64 * 768 * 4));
    float* msump  = (float*)(ws + alloc((size_t)64 * 4));
    float* hp     = (float*)(ws + alloc((size_t)48 * 256 * 4));
    float* summask= (float*)(ws + alloc((size_t)4096 * 4));
    int* counts   = (int*)(ws + alloc((size_t)8 * NNODES * 4));
    int* offs     = (int*)(ws + alloc((size_t)8 * 1026 * 4));
    int* cursor   = (int*)(ws + alloc((size_t)8 * NNODES * 4));
    int* eord     = (int*)(ws + alloc((size_t)8 * EE * 4));
    bf16* Abf     = (bf16*)(ws + alloc((size_t)32768 * 768 * 2));
    bf16* pooledh = (bf16*)(ws + alloc((size_t)4096 * 1024 * 2));
    bf16* pooled  = (bf16*)(ws + alloc((size_t)8192 * 768 * 2));
    float* h      = (float*)(ws + alloc((size_t)8 * HSTRIDE * 256 * 4));
    bf16* hbf     = (bf16*)(ws + alloc((size_t)8 * HSTRIDE * 256 * 2));
    bf16* qkv     = (bf16*)(ws + alloc((size_t)8 * HSTRIDE * 768 * 2));

    // L1: gathers + all independent preprocessing
    k_prep<<<11497, 256, 0, stream>>>(nodes, node_mask, entity_table, Abf, pooled,
                                      mlp_w1, mlp_w2, ntw_w, proj_w, gnn_wq, gnn_wk, gnn_wv,
                                      type_table, type_proj_w, edge_tt, gnn_we,
                                      cls_w, cls2_w, cls_b, cls2_b,
                                      sentence, mask, word_embed,
                                      w1t, w2t, ntwbf, projt, wqkvt,
                                      tpe, etewe, weff, beff, tvp, msump, counts);
    // L2: fold ntw@proj + tvred + summask + CSR count
    k_mid<<<548, 256, 0, stream>>>(projt, ntwbf, wnpt, tvp, msump, tv,
                                   node_mask, summask, edges, counts);
    // L3: clean GEMM1 + pooled epilogue + CSR scan
    k_mlp1_scan<<<2056, 256, 0, stream>>>(Abf, w1t, mlp_b1, node_mask, pooledh,
                                          counts, offs, cursor);
    // L4: gemm2 + h-row0 partials + CSR scatter
    k_mega4<<<752, 256, 0, stream>>>(pooledh, w2t, pooled, mlp_b2, summask,
                                     tv, proj_w, hp, edges, cursor, eord);
    // L5: folded np-GEMM with type-embed epilogue + row0/pad assembly
    k_mega5<<<256, 256, 0, stream>>>(pooled, wnpt, h, hbf, proj_b, node_types, tpe, hp);

    for (int l = 0; l < 2; l++) {
        gemm_bt<0><<<390, 256, 0, stream>>>(hbf, wqkvt + l * 196608, qkv, nullptr, nullptr,
                                            nullptr, 8320, 768, 256, 6, 0);
        k_gnn_node<<<8 * NNODES, 256, 0, stream>>>(edges, edge_types, offs, eord,
                                                   etewe + l * 12800, qkv, h, hbf);
    }
    k_cls<<<400, 256, 0, stream>>>(h, tv, weff, beff, (float*)d_out);
}